// Round 15
// baseline (257.841 us; speedup 1.0000x reference)
//
#include <hip/hip_runtime.h>
#include <hip/hip_bf16.h>

typedef short s16x8 __attribute__((ext_vector_type(8)));   // 8 bf16 (4 VGPRs)
typedef float f32x4 __attribute__((ext_vector_type(4)));

#define LOG2E 1.4426950408889634f

__device__ __forceinline__ float bfl(unsigned w) { return __uint_as_float(w << 16); }
__device__ __forceinline__ float bfh(unsigned w) { return __uint_as_float(w & 0xffff0000u); }
__device__ __forceinline__ float ubf(ushort u) { return __uint_as_float((unsigned)u << 16); }
__device__ __forceinline__ unsigned f2bf(float f) {
    unsigned u = __float_as_uint(f);
    return (u + 0x7fffu + ((u >> 16) & 1u)) >> 16;  // RNE, finite data
}

// ---------------- CSR build ----------------
__global__ void deg_kernel(const int* __restrict__ dst, int* __restrict__ deg, int E) {
    int e = blockIdx.x * blockDim.x + threadIdx.x;
    if (e < E) atomicAdd(&deg[dst[e]], 1);
}

__global__ void scan_reduce(const int* __restrict__ deg, int* __restrict__ bsum, int n) {
    __shared__ int sh[256];
    int t = threadIdx.x;
    int i = blockIdx.x * 256 + t;
    sh[t] = (i < n) ? deg[i] : 0;
    __syncthreads();
    for (int s = 128; s > 0; s >>= 1) {
        if (t < s) sh[t] += sh[t + s];
        __syncthreads();
    }
    if (t == 0) bsum[blockIdx.x] = sh[0];
}

__global__ void scan_blocks(const int* __restrict__ bsum, int* __restrict__ boff,
                            int nb, int* __restrict__ off, int n) {
    __shared__ int sh[256];
    int t = threadIdx.x;
    int v = (t < nb) ? bsum[t] : 0;
    sh[t] = v;
    __syncthreads();
    for (int d = 1; d < 256; d <<= 1) {
        int x = (t >= d) ? sh[t - d] : 0;
        __syncthreads();
        sh[t] += x;
        __syncthreads();
    }
    if (t < nb) boff[t] = sh[t] - v;
    if (t == 255) off[n] = sh[255];
}

__global__ void scan_apply(const int* __restrict__ deg, const int* __restrict__ boff,
                           int* __restrict__ off, int* __restrict__ cursor, int n) {
    __shared__ int sh[256];
    int t = threadIdx.x;
    int i = blockIdx.x * 256 + t;
    int v = (i < n) ? deg[i] : 0;
    sh[t] = v;
    __syncthreads();
    for (int d = 1; d < 256; d <<= 1) {
        int x = (t >= d) ? sh[t - d] : 0;
        __syncthreads();
        sh[t] += x;
        __syncthreads();
    }
    int ex = sh[t] - v + boff[blockIdx.x];
    if (i < n) {
        off[i] = ex;
        cursor[i] = ex;
    }
}

__global__ void scatter_kernel(const int* __restrict__ src, const int* __restrict__ dst,
                               int* __restrict__ cursor, int* __restrict__ srcs, int E) {
    int e = blockIdx.x * blockDim.x + threadIdx.x;
    if (e < E) {
        int p = atomicAdd(&cursor[dst[e]], 1);
        srcs[p] = src[e];
    }
}

// ---------------- prep_all: fused weight preprocessing + buffer zeroing ----------
__global__ void prep_all(const float* __restrict__ Wq1, const float* __restrict__ bq1,
                         const float* __restrict__ Wk1,
                         const float* __restrict__ Wq2, const float* __restrict__ bq2,
                         const float* __restrict__ Wk2,
                         const float* __restrict__ Wv2, const float* __restrict__ Ws2,
                         float* __restrict__ c1, float* __restrict__ wcat,
                         ushort* __restrict__ bfragY, ushort* __restrict__ B192,
                         int* __restrict__ deg, unsigned* __restrict__ pool,
                         int n, int nbdeg, int poolsz) {
    int b = blockIdx.x, t = threadIdx.x;
    if (b == 0) {
        if (t < 18) {
            int h = t / 9, rr = t % 9, r = rr / 3, rp = rr % 3;
            float s = 0.f;
            for (int d = 0; d < 32; ++d)
                s += Wq1[r * 64 + h * 32 + d] * Wk1[rp * 64 + h * 32 + d];
            c1[t] = s;
        } else if (t < 24) {
            int u = t - 18, h = u / 3, rp = u % 3;
            float s = 0.f;
            for (int d = 0; d < 32; ++d)
                s += bq1[h * 32 + d] * Wk1[rp * 64 + h * 32 + d];
            c1[t] = s;
        } else if (t >= 64 && t < 192) {
            int cc = t - 64, h = cc >> 6, kp = cc & 63;
            float s = 0.f;
            for (int d = 0; d < 64; ++d)
                s += bq2[h * 64 + d] * Wk2[kp * 128 + h * 64 + d];
            wcat[cc] = s;
        }
    } else if (b < 33) {
        int idx = (b - 1) * 256 + t;  // 0..8191 = Mcat element (k, cc)
        int k = idx >> 7, cc = idx & 127, h = cc >> 6, kp = cc & 63;
        float s = 0.f;
        for (int d = 0; d < 64; ++d)
            s += Wq2[k * 128 + h * 64 + d] * Wk2[kp * 128 + h * 64 + d];
        int frag = ((cc >> 4) << 1) | (k >> 5);
        int l = (cc & 15) | (((k >> 3) & 3) << 4);
        bfragY[(size_t)frag * 512 + l * 8 + (k & 7)] = (ushort)f2bf(s);
    } else if (b < 45) {
        int tt = (b - 33) * 256 + t;  // 0..3071 (48 frags x 64 lanes)
        int frag = tt >> 6, l = tt & 63;
        int ct = frag / 6, ks = frag % 6;
        int c = ct * 16 + (l & 15);
        int kbase = ks * 32 + ((l >> 4) << 3);
#pragma unroll
        for (int e = 0; e < 8; ++e) {
            int k = kbase + e;
            float v;
            if (k < 64) v = (c < 64) ? Wv2[k * 128 + c] : 0.f;
            else if (k < 128) v = (c >= 64) ? Wv2[(k - 64) * 128 + c] : 0.f;
            else v = Ws2[(k - 128) * 128 + c];
            B192[(size_t)frag * 512 + l * 8 + e] = (ushort)f2bf(v);
        }
    } else if (b < 45 + nbdeg) {
        int i = (b - 45) * 256 + t;
        if (i < n) deg[i] = 0;
    } else {
        int i = (b - 45 - nbdeg) * 256 + t;
        if (i < poolsz) pool[i] = 0;
    }
}

// ---------------- attn1f: fused layer-1 attention (no-max softmax) ----------------
__global__ __launch_bounds__(256) void attn1f(
        const float* __restrict__ x, const float* __restrict__ c1,
        const float* __restrict__ Wv, const float* __restrict__ bv,
        const float* __restrict__ Ws, const float* __restrict__ bs,
        const int* __restrict__ off, const int* __restrict__ srcs,
        unsigned* __restrict__ h1b, int n) {
    int lane = threadIdx.x & 63;
    int g = lane >> 3, sl = lane & 7;
    int i = (blockIdx.x * (blockDim.x >> 6) + (threadIdx.x >> 6)) * 8 + g;
    bool act = i < n;
    int ic = act ? i : 0;
    float x0 = x[ic * 3], x1 = x[ic * 3 + 1], x2 = x[ic * 3 + 2];
    float y0[3], y1[3];
#pragma unroll
    for (int rp = 0; rp < 3; ++rp) {
        y0[rp] = x0 * c1[rp] + x1 * c1[3 + rp] + x2 * c1[6 + rp] + c1[18 + rp];
        y1[rp] = x0 * c1[9 + rp] + x1 * c1[12 + rp] + x2 * c1[15 + rp] + c1[21 + rp];
    }
    const float SC = 0.17677669529663688f * LOG2E;  // scale/sqrt(32) * log2(e)
    int e0 = act ? off[ic] : 0, e1 = act ? off[ic + 1] : 0;
    float d0 = 0.f, d1 = 0.f;
    float a0x = 0.f, a0y = 0.f, a0z = 0.f, a1x = 0.f, a1y = 0.f, a1z = 0.f;
    for (int e = e0 + sl; e < e1; e += 8) {
        int j = srcs[e];
        float xj0 = x[j * 3], xj1 = x[j * 3 + 1], xj2 = x[j * 3 + 2];
        float p0 = exp2f((y0[0] * xj0 + y0[1] * xj1 + y0[2] * xj2) * SC);
        float p1 = exp2f((y1[0] * xj0 + y1[1] * xj1 + y1[2] * xj2) * SC);
        d0 += p0; a0x += p0 * xj0; a0y += p0 * xj1; a0z += p0 * xj2;
        d1 += p1; a1x += p1 * xj0; a1y += p1 * xj1; a1z += p1 * xj2;
    }
#pragma unroll
    for (int mask = 1; mask <= 4; mask <<= 1) {
        d0 += __shfl_xor(d0, mask); d1 += __shfl_xor(d1, mask);
        a0x += __shfl_xor(a0x, mask); a0y += __shfl_xor(a0y, mask);
        a0z += __shfl_xor(a0z, mask); a1x += __shfl_xor(a1x, mask);
        a1y += __shfl_xor(a1y, mask); a1z += __shfl_xor(a1z, mask);
    }
    if (!act) return;
    int head = sl >> 2;
    float dh = head ? d1 : d0;
    float inv = 1.f / fmaxf(dh, 1e-16f);
    float sg = dh > 0.f ? 1.f : 0.f;
    float Ax = (head ? a1x : a0x) * inv;
    float Ay = (head ? a1y : a0y) * inv;
    float Az = (head ? a1z : a0z) * inv;
    unsigned pk[4];
#pragma unroll
    for (int u = 0; u < 4; ++u) {
        int c = sl * 8 + 2 * u;
        float2 wv0 = *(const float2*)&Wv[c], wv1 = *(const float2*)&Wv[64 + c],
               wv2 = *(const float2*)&Wv[128 + c];
        float2 ws0 = *(const float2*)&Ws[c], ws1 = *(const float2*)&Ws[64 + c],
               ws2 = *(const float2*)&Ws[128 + c];
        float2 bbv = *(const float2*)&bv[c];
        float2 bbs = *(const float2*)&bs[c];
        float v0 = Ax * wv0.x + Ay * wv1.x + Az * wv2.x + sg * bbv.x +
                   x0 * ws0.x + x1 * ws1.x + x2 * ws2.x + bbs.x;
        float v1 = Ax * wv0.y + Ay * wv1.y + Az * wv2.y + sg * bbv.y +
                   x0 * ws0.y + x1 * ws1.y + x2 * ws2.y + bbs.y;
        pk[u] = f2bf(fmaxf(v0, 0.f)) | (f2bf(fmaxf(v1, 0.f)) << 16);
    }
    uint4 pa = {pk[0], pk[1], pk[2], pk[3]};
    *(uint4*)&h1b[(size_t)i * 32 + sl * 4] = pa;
}

// ---------------- lin2Y: Y' = h1 @ Mcat + wcat (MFMA, N x 128 f32) ---------------
__global__ __launch_bounds__(256) void lin2Y(const ushort* __restrict__ h1b,
                                             const ushort* __restrict__ bfragY,
                                             const float* __restrict__ wcat,
                                             float* __restrict__ Yp, int n) {
    int node0 = blockIdx.x * 16;
    int w = threadIdx.x >> 6, l = threadIdx.x & 63;
    int arow = node0 + (l & 15);
    if (arow >= n) arow = n - 1;
    s16x8 a0 = *(const s16x8*)&h1b[(size_t)arow * 64 + ((l >> 4) << 3)];
    s16x8 a1 = *(const s16x8*)&h1b[(size_t)arow * 64 + 32 + ((l >> 4) << 3)];
    int cl = l & 15;
#pragma unroll
    for (int qq = 0; qq < 2; ++qq) {
        int ct = w * 2 + qq;
        s16x8 b0 = *(const s16x8*)&bfragY[(size_t)(ct * 2 + 0) * 512 + l * 8];
        s16x8 b1 = *(const s16x8*)&bfragY[(size_t)(ct * 2 + 1) * 512 + l * 8];
        f32x4 acc = {0.f, 0.f, 0.f, 0.f};
        acc = __builtin_amdgcn_mfma_f32_16x16x32_bf16(a0, b0, acc, 0, 0, 0);
        acc = __builtin_amdgcn_mfma_f32_16x16x32_bf16(a1, b1, acc, 0, 0, 0);
        int cg = ct * 16 + cl;
        float bb = wcat[cg];
#pragma unroll
        for (int r = 0; r < 4; ++r) {
            int node = node0 + ((l >> 4) << 2) + r;
            if (node < n) Yp[(size_t)node * 128 + cg] = acc[r] + bb;
        }
    }
}

// ---------------- attn2s (pass A): scores only -> pbuf[e] = (p0, p1) f32 ----------
// Octet-split: og=lane>>3 takes every-8th edge; sl=lane&7 owns h-channels 8sl..+7.
// No accumulators, no merge — pass B recomputes d as a plain sum of p.
__global__ __launch_bounds__(256) void attn2s(
        const float* __restrict__ Yp, const unsigned* __restrict__ h1u,
        const int* __restrict__ off, const int* __restrict__ srcs,
        float2* __restrict__ pbuf, int n) {
    int i = blockIdx.x * (blockDim.x >> 6) + (threadIdx.x >> 6);
    int lane = threadIdx.x & 63;
    if (i >= n) return;
    int og = lane >> 3, sl = lane & 7;
    int e0 = off[i], e1 = off[i + 1];
    const float SC = 0.125f * LOG2E;  // 1/sqrt(64) * log2(e)
    float4 ya0 = *(const float4*)&Yp[(size_t)i * 128 + 8 * sl];
    float4 ya1 = *(const float4*)&Yp[(size_t)i * 128 + 8 * sl + 4];
    float4 yb0 = *(const float4*)&Yp[(size_t)i * 128 + 64 + 8 * sl];
    float4 yb1 = *(const float4*)&Yp[(size_t)i * 128 + 64 + 8 * sl + 4];
    for (int e = e0 + og; e < e1; e += 8) {
        int j = srcs[e];
        uint4 hb = *(const uint4*)&h1u[(size_t)j * 32 + 4 * sl];
        float t0 = ya0.x * bfl(hb.x) + ya0.y * bfh(hb.x) + ya0.z * bfl(hb.y) +
                   ya0.w * bfh(hb.y) + ya1.x * bfl(hb.z) + ya1.y * bfh(hb.z) +
                   ya1.z * bfl(hb.w) + ya1.w * bfh(hb.w);
        float t1 = yb0.x * bfl(hb.x) + yb0.y * bfh(hb.x) + yb0.z * bfl(hb.y) +
                   yb0.w * bfh(hb.y) + yb1.x * bfl(hb.z) + yb1.y * bfh(hb.z) +
                   yb1.z * bfl(hb.w) + yb1.w * bfh(hb.w);
        t0 += __shfl_xor(t0, 1); t0 += __shfl_xor(t0, 2); t0 += __shfl_xor(t0, 4);
        t1 += __shfl_xor(t1, 1); t1 += __shfl_xor(t1, 2); t1 += __shfl_xor(t1, 4);
        if (sl == 0) {
            float2 p = {exp2f(t0 * SC), exp2f(t1 * SC)};
            pbuf[e] = p;
        }
    }
}

// ---------------- attn2pv (pass B): a_h = sum p*h, d = sum p; zero shuffles -------
// Wave = node; lane = h-channel (64 lanes = full h1 row, coalesced 128B/edge).
// srcs[e]/pbuf[e] are wave-uniform (scalar loads). Writes a01 bf16 + sig2.
__global__ __launch_bounds__(256) void attn2pv(
        const ushort* __restrict__ h1w, const int* __restrict__ off,
        const int* __restrict__ srcs, const float2* __restrict__ pbuf,
        ushort* __restrict__ a01, float2* __restrict__ sig2, int n) {
    int i = blockIdx.x * (blockDim.x >> 6) + (threadIdx.x >> 6);
    int lane = threadIdx.x & 63;
    if (i >= n) return;
    int e0 = off[i], e1 = off[i + 1];
    float a0 = 0.f, a1 = 0.f, d0 = 0.f, d1 = 0.f;
    for (int e = e0; e < e1; ++e) {
        int j = srcs[e];
        float2 p = pbuf[e];
        float h = ubf(h1w[(size_t)j * 64 + lane]);
        a0 += p.x * h; a1 += p.y * h;
        d0 += p.x; d1 += p.y;
    }
    float i0 = 1.f / fmaxf(d0, 1e-16f), i1 = 1.f / fmaxf(d1, 1e-16f);
    a01[(size_t)i * 128 + lane] = (ushort)f2bf(a0 * i0);
    a01[(size_t)i * 128 + 64 + lane] = (ushort)f2bf(a1 * i1);
    if (lane == 0) {
        float2 sg = {d0 > 0.f ? 1.f : 0.f, d1 > 0.f ? 1.f : 0.f};
        sig2[i] = sg;
    }
}

// ---------------- epi2: out = relu([a0|a1|h1]@B192 + sigma*bv + bs) + LDS pool ----
__global__ __launch_bounds__(256) void epi2(
        const ushort* __restrict__ a01, const ushort* __restrict__ h1b,
        const ushort* __restrict__ B192, const float* __restrict__ bv,
        const float* __restrict__ bs, const float* __restrict__ sig2,
        const int* __restrict__ batch, unsigned* __restrict__ pool, int n) {
    __shared__ float po[16][128];
    __shared__ int pg[16];
    int node0 = blockIdx.x * 16;
    int w = threadIdx.x >> 6, l = threadIdx.x & 63;
    int arow = node0 + (l & 15);
    int arc = (arow < n) ? arow : (n - 1);
    int koff = (l >> 4) << 3;
    s16x8 af[6];
    af[0] = *(const s16x8*)&a01[(size_t)arc * 128 + 0 + koff];
    af[1] = *(const s16x8*)&a01[(size_t)arc * 128 + 32 + koff];
    af[2] = *(const s16x8*)&a01[(size_t)arc * 128 + 64 + koff];
    af[3] = *(const s16x8*)&a01[(size_t)arc * 128 + 96 + koff];
    af[4] = *(const s16x8*)&h1b[(size_t)arc * 64 + 0 + koff];
    af[5] = *(const s16x8*)&h1b[(size_t)arc * 64 + 32 + koff];
    if (threadIdx.x < 16)
        pg[threadIdx.x] = (node0 + threadIdx.x < n) ? batch[node0 + threadIdx.x] : -1;
    int cl = l & 15;
#pragma unroll
    for (int qq = 0; qq < 2; ++qq) {
        int ct = w * 2 + qq;
        f32x4 acc = {0.f, 0.f, 0.f, 0.f};
#pragma unroll
        for (int ks = 0; ks < 6; ++ks) {
            s16x8 b = *(const s16x8*)&B192[(size_t)(ct * 6 + ks) * 512 + l * 8];
            acc = __builtin_amdgcn_mfma_f32_16x16x32_bf16(af[ks], b, acc, 0, 0, 0);
        }
        int cg = ct * 16 + cl;
        int head = cg >> 6;
        float bbs = bs[cg], bbv = bv[cg];
#pragma unroll
        for (int r = 0; r < 4; ++r) {
            int row = ((l >> 4) << 2) + r;
            int node = node0 + row;
            float sg = (node < n) ? sig2[node * 2 + head] : 0.f;
            po[row][cg] = fmaxf(acc[r] + sg * bbv + bbs, 0.f);
        }
    }
    __syncthreads();
    int t = threadIdx.x;
    if (t < 128) {
        int curg = -1;
        float mx = 0.f;
        for (int r = 0; r < 16; ++r) {
            int g = pg[r];
            if (g < 0) continue;
            if (g != curg) {
                if (curg >= 0) atomicMax(&pool[(size_t)curg * 128 + t], __float_as_uint(mx));
                curg = g;
                mx = 0.f;
            }
            mx = fmaxf(mx, po[r][t]);
        }
        if (curg >= 0) atomicMax(&pool[(size_t)curg * 128 + t], __float_as_uint(mx));
    }
}

// ---------------- MLP head ----------------
__global__ void head_kernel(const unsigned* __restrict__ pbits,
                            const float* __restrict__ W1, const float* __restrict__ b1,
                            const float* __restrict__ W2, const float* __restrict__ b2,
                            const float* __restrict__ W3, const float* __restrict__ b3,
                            float* __restrict__ out, int G) {
    int g = blockIdx.x;
    int t = threadIdx.x;  // 128 threads
    __shared__ float ps[128], xl[32], y[128];
    ps[t] = __uint_as_float(pbits[g * 128 + t]);
    __syncthreads();
    if (t < 32) {
        float a = b1[t];
        for (int k = 0; k < 128; ++k) a += ps[k] * W1[k * 32 + t];
        a = fmaxf(a, 0.f);
        xl[t] = a;
        out[G * 40 + g * 32 + t] = a;
    }
    __syncthreads();
    {
        float a = b2[t];
        for (int k = 0; k < 32; ++k) a += xl[k] * W2[k * 128 + t];
        y[t] = fmaxf(a, 0.f);
    }
    __syncthreads();
    if (t < 40) {
        float a = b3[t];
        for (int k = 0; k < 128; ++k) a += y[k] * W3[k * 40 + t];  // W3 is (128,40)
        out[g * 40 + t] = a;
    }
}

extern "C" void kernel_launch(void* const* d_in, const int* in_sizes, int n_in,
                              void* d_out, int out_size, void* d_ws, size_t ws_size,
                              hipStream_t stream) {
    const float* x = (const float*)d_in[0];
    const int* eidx = (const int*)d_in[1];
    const int* batch = (const int*)d_in[2];
    const float *Wq1 = (const float*)d_in[3], *bq1 = (const float*)d_in[4];
    const float *Wk1 = (const float*)d_in[5], *bk1 = (const float*)d_in[6];
    const float *Wv1 = (const float*)d_in[7], *bv1 = (const float*)d_in[8];
    const float *Ws1 = (const float*)d_in[9], *bs1 = (const float*)d_in[10];
    const float *Wq2 = (const float*)d_in[11], *bq2 = (const float*)d_in[12];
    const float *Wk2 = (const float*)d_in[13], *bk2 = (const float*)d_in[14];
    const float *Wv2 = (const float*)d_in[15], *bv2 = (const float*)d_in[16];
    const float *Ws2 = (const float*)d_in[17], *bs2 = (const float*)d_in[18];
    const float *W1 = (const float*)d_in[19], *b1 = (const float*)d_in[20];
    const float *W2 = (const float*)d_in[21], *b2 = (const float*)d_in[22];
    const float *W3 = (const float*)d_in[23], *b3 = (const float*)d_in[24];
    (void)bk1; (void)bk2;  // bk terms cancel in softmax (constant per-dst shift)

    const int N = in_sizes[0] / 3;
    const int E = in_sizes[1] / 2;
    const int G = out_size / 72;  // 40 + 32 per graph
    const int* esrc = eidx;
    const int* edst = eidx + E;
    const int NB = (N + 255) / 256;
    const int POOLSZ = G * 128;
    const int PB = (POOLSZ + 255) / 256;

    char* w = (char*)d_ws;
    size_t o = 0;
    auto alloc = [&](size_t bytes) {
        void* p = w + o;
        o = (o + bytes + 255) & ~(size_t)255;
        return p;
    };
    float* c1buf = (float*)alloc(24 * 4);
    float* wcat = (float*)alloc(128 * 4);
    ushort* bfragY = (ushort*)alloc(16 * 512 * 2);
    ushort* B192 = (ushort*)alloc(48 * 512 * 2);
    unsigned* h1b = (unsigned*)alloc((size_t)N * 32 * 4);   // N x 64 bf16
    float* Yp = (float*)alloc((size_t)N * 128 * 4);
    ushort* a01 = (ushort*)alloc((size_t)N * 128 * 2);      // N x 128 bf16
    float* sig2 = (float*)alloc((size_t)N * 2 * 4);
    float2* pbuf = (float2*)alloc((size_t)E * 8);           // per-edge (p0,p1)
    int* deg = (int*)alloc((size_t)N * 4);
    int* off = (int*)alloc((size_t)(N + 1) * 4);
    int* cursor = (int*)alloc((size_t)N * 4);
    int* srcs = (int*)alloc((size_t)E * 4);
    unsigned* pool = (unsigned*)alloc((size_t)POOLSZ * 4);
    int* bsum = (int*)alloc(256 * 4);
    int* boff = (int*)alloc(256 * 4);
    (void)ws_size;

    // fused prep (weights -> c1/wcat/bfragY/B192) + zero deg + zero pool
    prep_all<<<45 + NB + PB, 256, 0, stream>>>(Wq1, bq1, Wk1, Wq2, bq2, Wk2, Wv2, Ws2,
                                               c1buf, wcat, bfragY, B192, deg, pool,
                                               N, NB, POOLSZ);

    // CSR by destination
    deg_kernel<<<(E + 255) / 256, 256, 0, stream>>>(edst, deg, E);
    scan_reduce<<<NB, 256, 0, stream>>>(deg, bsum, N);
    scan_blocks<<<1, 256, 0, stream>>>(bsum, boff, NB, off, N);
    scan_apply<<<NB, 256, 0, stream>>>(deg, boff, off, cursor, N);
    scatter_kernel<<<(E + 255) / 256, 256, 0, stream>>>(esrc, edst, cursor, srcs, E);

    // layer 1 (fused: scores via x^T M x, PV via (sum p x), V/skip/relu epilogue)
    attn1f<<<(N + 31) / 32, 256, 0, stream>>>(x, c1buf, Wv1, bv1, Ws1, bs1, off, srcs,
                                              h1b, N);

    // layer 2 (two-pass attention: scores -> pbuf, then shuffle-free PV)
    lin2Y<<<(N + 15) / 16, 256, 0, stream>>>((const ushort*)h1b, bfragY, wcat, Yp, N);
    attn2s<<<(N + 3) / 4, 256, 0, stream>>>(Yp, h1b, off, srcs, pbuf, N);
    attn2pv<<<(N + 3) / 4, 256, 0, stream>>>((const ushort*)h1b, off, srcs, pbuf,
                                             a01, (float2*)sig2, N);
    epi2<<<(N + 15) / 16, 256, 0, stream>>>(a01, (const ushort*)h1b, B192,
                                            bv2, bs2, sig2, batch, pool, N);

    // head
    head_kernel<<<G, 128, 0, stream>>>(pool, W1, b1, W2, b2, W3, b3, (float*)d_out, G);
}

// Round 16
// 198.235 us; speedup vs baseline: 1.3007x; 1.3007x over previous
//
#include <hip/hip_runtime.h>
#include <hip/hip_bf16.h>

typedef short s16x8 __attribute__((ext_vector_type(8)));   // 8 bf16 (4 VGPRs)
typedef float f32x4 __attribute__((ext_vector_type(4)));

#define LOG2E 1.4426950408889634f

__device__ __forceinline__ float bfl(unsigned w) { return __uint_as_float(w << 16); }
__device__ __forceinline__ float bfh(unsigned w) { return __uint_as_float(w & 0xffff0000u); }
__device__ __forceinline__ unsigned f2bf(float f) {
    unsigned u = __float_as_uint(f);
    return (u + 0x7fffu + ((u >> 16) & 1u)) >> 16;  // RNE, finite data
}

// ---------------- CSR build ----------------
__global__ void deg_kernel(const int* __restrict__ dst, int* __restrict__ deg, int E) {
    int e = blockIdx.x * blockDim.x + threadIdx.x;
    if (e < E) atomicAdd(&deg[dst[e]], 1);
}

__global__ void scan_reduce(const int* __restrict__ deg, int* __restrict__ bsum, int n) {
    __shared__ int sh[256];
    int t = threadIdx.x;
    int i = blockIdx.x * 256 + t;
    sh[t] = (i < n) ? deg[i] : 0;
    __syncthreads();
    for (int s = 128; s > 0; s >>= 1) {
        if (t < s) sh[t] += sh[t + s];
        __syncthreads();
    }
    if (t == 0) bsum[blockIdx.x] = sh[0];
}

__global__ void scan_blocks(const int* __restrict__ bsum, int* __restrict__ boff,
                            int nb, int* __restrict__ off, int n) {
    __shared__ int sh[256];
    int t = threadIdx.x;
    int v = (t < nb) ? bsum[t] : 0;
    sh[t] = v;
    __syncthreads();
    for (int d = 1; d < 256; d <<= 1) {
        int x = (t >= d) ? sh[t - d] : 0;
        __syncthreads();
        sh[t] += x;
        __syncthreads();
    }
    if (t < nb) boff[t] = sh[t] - v;
    if (t == 255) off[n] = sh[255];
}

__global__ void scan_apply(const int* __restrict__ deg, const int* __restrict__ boff,
                           int* __restrict__ off, int* __restrict__ cursor, int n) {
    __shared__ int sh[256];
    int t = threadIdx.x;
    int i = blockIdx.x * 256 + t;
    int v = (i < n) ? deg[i] : 0;
    sh[t] = v;
    __syncthreads();
    for (int d = 1; d < 256; d <<= 1) {
        int x = (t >= d) ? sh[t - d] : 0;
        __syncthreads();
        sh[t] += x;
        __syncthreads();
    }
    int ex = sh[t] - v + boff[blockIdx.x];
    if (i < n) {
        off[i] = ex;
        cursor[i] = ex;
    }
}

__global__ void scatter_kernel(const int* __restrict__ src, const int* __restrict__ dst,
                               int* __restrict__ cursor, int* __restrict__ srcs, int E) {
    int e = blockIdx.x * blockDim.x + threadIdx.x;
    if (e < E) {
        int p = atomicAdd(&cursor[dst[e]], 1);
        srcs[p] = src[e];
    }
}

// ---------------- prep_all: fused weight preprocessing + buffer zeroing ----------
__global__ void prep_all(const float* __restrict__ Wq1, const float* __restrict__ bq1,
                         const float* __restrict__ Wk1,
                         const float* __restrict__ Wq2, const float* __restrict__ bq2,
                         const float* __restrict__ Wk2,
                         const float* __restrict__ Wv2, const float* __restrict__ Ws2,
                         float* __restrict__ c1, float* __restrict__ wcat,
                         ushort* __restrict__ bfragY, ushort* __restrict__ B192,
                         int* __restrict__ deg, unsigned* __restrict__ pool,
                         int n, int nbdeg, int poolsz) {
    int b = blockIdx.x, t = threadIdx.x;
    if (b == 0) {
        if (t < 18) {
            int h = t / 9, rr = t % 9, r = rr / 3, rp = rr % 3;
            float s = 0.f;
            for (int d = 0; d < 32; ++d)
                s += Wq1[r * 64 + h * 32 + d] * Wk1[rp * 64 + h * 32 + d];
            c1[t] = s;
        } else if (t < 24) {
            int u = t - 18, h = u / 3, rp = u % 3;
            float s = 0.f;
            for (int d = 0; d < 32; ++d)
                s += bq1[h * 32 + d] * Wk1[rp * 64 + h * 32 + d];
            c1[t] = s;
        } else if (t >= 64 && t < 192) {
            int cc = t - 64, h = cc >> 6, kp = cc & 63;
            float s = 0.f;
            for (int d = 0; d < 64; ++d)
                s += bq2[h * 64 + d] * Wk2[kp * 128 + h * 64 + d];
            wcat[cc] = s;
        }
    } else if (b < 33) {
        int idx = (b - 1) * 256 + t;  // 0..8191 = Mcat element (k, cc)
        int k = idx >> 7, cc = idx & 127, h = cc >> 6, kp = cc & 63;
        float s = 0.f;
        for (int d = 0; d < 64; ++d)
            s += Wq2[k * 128 + h * 64 + d] * Wk2[kp * 128 + h * 64 + d];
        int frag = ((cc >> 4) << 1) | (k >> 5);
        int l = (cc & 15) | (((k >> 3) & 3) << 4);
        bfragY[(size_t)frag * 512 + l * 8 + (k & 7)] = (ushort)f2bf(s);
    } else if (b < 45) {
        int tt = (b - 33) * 256 + t;  // 0..3071 (48 frags x 64 lanes)
        int frag = tt >> 6, l = tt & 63;
        int ct = frag / 6, ks = frag % 6;
        int c = ct * 16 + (l & 15);
        int kbase = ks * 32 + ((l >> 4) << 3);
#pragma unroll
        for (int e = 0; e < 8; ++e) {
            int k = kbase + e;
            float v;
            if (k < 64) v = (c < 64) ? Wv2[k * 128 + c] : 0.f;
            else if (k < 128) v = (c >= 64) ? Wv2[(k - 64) * 128 + c] : 0.f;
            else v = Ws2[(k - 128) * 128 + c];
            B192[(size_t)frag * 512 + l * 8 + e] = (ushort)f2bf(v);
        }
    } else if (b < 45 + nbdeg) {
        int i = (b - 45) * 256 + t;
        if (i < n) deg[i] = 0;
    } else {
        int i = (b - 45 - nbdeg) * 256 + t;
        if (i < poolsz) pool[i] = 0;
    }
}

// ---------------- attn1f: fused layer-1 attention (no-max softmax) ----------------
__global__ __launch_bounds__(256) void attn1f(
        const float* __restrict__ x, const float* __restrict__ c1,
        const float* __restrict__ Wv, const float* __restrict__ bv,
        const float* __restrict__ Ws, const float* __restrict__ bs,
        const int* __restrict__ off, const int* __restrict__ srcs,
        unsigned* __restrict__ h1b, int n) {
    int lane = threadIdx.x & 63;
    int g = lane >> 3, sl = lane & 7;
    int i = (blockIdx.x * (blockDim.x >> 6) + (threadIdx.x >> 6)) * 8 + g;
    bool act = i < n;
    int ic = act ? i : 0;
    float x0 = x[ic * 3], x1 = x[ic * 3 + 1], x2 = x[ic * 3 + 2];
    float y0[3], y1[3];
#pragma unroll
    for (int rp = 0; rp < 3; ++rp) {
        y0[rp] = x0 * c1[rp] + x1 * c1[3 + rp] + x2 * c1[6 + rp] + c1[18 + rp];
        y1[rp] = x0 * c1[9 + rp] + x1 * c1[12 + rp] + x2 * c1[15 + rp] + c1[21 + rp];
    }
    const float SC = 0.17677669529663688f * LOG2E;  // scale/sqrt(32) * log2(e)
    int e0 = act ? off[ic] : 0, e1 = act ? off[ic + 1] : 0;
    float d0 = 0.f, d1 = 0.f;
    float a0x = 0.f, a0y = 0.f, a0z = 0.f, a1x = 0.f, a1y = 0.f, a1z = 0.f;
    for (int e = e0 + sl; e < e1; e += 8) {
        int j = srcs[e];
        float xj0 = x[j * 3], xj1 = x[j * 3 + 1], xj2 = x[j * 3 + 2];
        float p0 = exp2f((y0[0] * xj0 + y0[1] * xj1 + y0[2] * xj2) * SC);
        float p1 = exp2f((y1[0] * xj0 + y1[1] * xj1 + y1[2] * xj2) * SC);
        d0 += p0; a0x += p0 * xj0; a0y += p0 * xj1; a0z += p0 * xj2;
        d1 += p1; a1x += p1 * xj0; a1y += p1 * xj1; a1z += p1 * xj2;
    }
#pragma unroll
    for (int mask = 1; mask <= 4; mask <<= 1) {
        d0 += __shfl_xor(d0, mask); d1 += __shfl_xor(d1, mask);
        a0x += __shfl_xor(a0x, mask); a0y += __shfl_xor(a0y, mask);
        a0z += __shfl_xor(a0z, mask); a1x += __shfl_xor(a1x, mask);
        a1y += __shfl_xor(a1y, mask); a1z += __shfl_xor(a1z, mask);
    }
    if (!act) return;
    int head = sl >> 2;
    float dh = head ? d1 : d0;
    float inv = 1.f / fmaxf(dh, 1e-16f);
    float sg = dh > 0.f ? 1.f : 0.f;
    float Ax = (head ? a1x : a0x) * inv;
    float Ay = (head ? a1y : a0y) * inv;
    float Az = (head ? a1z : a0z) * inv;
    unsigned pk[4];
#pragma unroll
    for (int u = 0; u < 4; ++u) {
        int c = sl * 8 + 2 * u;
        float2 wv0 = *(const float2*)&Wv[c], wv1 = *(const float2*)&Wv[64 + c],
               wv2 = *(const float2*)&Wv[128 + c];
        float2 ws0 = *(const float2*)&Ws[c], ws1 = *(const float2*)&Ws[64 + c],
               ws2 = *(const float2*)&Ws[128 + c];
        float2 bbv = *(const float2*)&bv[c];
        float2 bbs = *(const float2*)&bs[c];
        float v0 = Ax * wv0.x + Ay * wv1.x + Az * wv2.x + sg * bbv.x +
                   x0 * ws0.x + x1 * ws1.x + x2 * ws2.x + bbs.x;
        float v1 = Ax * wv0.y + Ay * wv1.y + Az * wv2.y + sg * bbv.y +
                   x0 * ws0.y + x1 * ws1.y + x2 * ws2.y + bbs.y;
        pk[u] = f2bf(fmaxf(v0, 0.f)) | (f2bf(fmaxf(v1, 0.f)) << 16);
    }
    uint4 pa = {pk[0], pk[1], pk[2], pk[3]};
    *(uint4*)&h1b[(size_t)i * 32 + sl * 4] = pa;
}

// ---------------- lin2Y: Y' = h1 @ Mcat + wcat (MFMA, N x 128 bf16) --------------
__global__ __launch_bounds__(256) void lin2Y(const ushort* __restrict__ h1b,
                                             const ushort* __restrict__ bfragY,
                                             const float* __restrict__ wcat,
                                             ushort* __restrict__ Ypb, int n) {
    int node0 = blockIdx.x * 16;
    int w = threadIdx.x >> 6, l = threadIdx.x & 63;
    int arow = node0 + (l & 15);
    if (arow >= n) arow = n - 1;
    s16x8 a0 = *(const s16x8*)&h1b[(size_t)arow * 64 + ((l >> 4) << 3)];
    s16x8 a1 = *(const s16x8*)&h1b[(size_t)arow * 64 + 32 + ((l >> 4) << 3)];
    int cl = l & 15;
#pragma unroll
    for (int qq = 0; qq < 2; ++qq) {
        int ct = w * 2 + qq;
        s16x8 b0 = *(const s16x8*)&bfragY[(size_t)(ct * 2 + 0) * 512 + l * 8];
        s16x8 b1 = *(const s16x8*)&bfragY[(size_t)(ct * 2 + 1) * 512 + l * 8];
        f32x4 acc = {0.f, 0.f, 0.f, 0.f};
        acc = __builtin_amdgcn_mfma_f32_16x16x32_bf16(a0, b0, acc, 0, 0, 0);
        acc = __builtin_amdgcn_mfma_f32_16x16x32_bf16(a1, b1, acc, 0, 0, 0);
        int cg = ct * 16 + cl;
        float bb = wcat[cg];
#pragma unroll
        for (int r = 0; r < 4; ++r) {
            int node = node0 + ((l >> 4) << 2) + r;
            if (node < n) Ypb[(size_t)node * 128 + cg] = (ushort)f2bf(acc[r] + bb);
        }
    }
}

// ---------------- attn2: fused no-max softmax over h1 gathers (round-14 struct) ---
// Octet-split: og=lane>>3 takes every-8th edge; sl=lane&7 owns h-channels 8sl..+7.
// Y' read as bf16 (halves Yp traffic vs f32).
__global__ void attn2_kernel(const ushort* __restrict__ Ypb, const unsigned* __restrict__ h1u,
                             const int* __restrict__ off, const int* __restrict__ srcs,
                             unsigned* __restrict__ a01, float2* __restrict__ sig2, int n) {
    int i = blockIdx.x * (blockDim.x >> 6) + (threadIdx.x >> 6);
    int lane = threadIdx.x & 63;
    if (i >= n) return;
    int og = lane >> 3, sl = lane & 7;
    int e0 = off[i], e1 = off[i + 1];
    const float SC = 0.125f * LOG2E;  // 1/sqrt(64) * log2(e)
    uint4 yau = *(const uint4*)&Ypb[(size_t)i * 128 + 8 * sl];
    uint4 ybu = *(const uint4*)&Ypb[(size_t)i * 128 + 64 + 8 * sl];
    float ya[8], yb[8];
    ya[0] = bfl(yau.x); ya[1] = bfh(yau.x); ya[2] = bfl(yau.y); ya[3] = bfh(yau.y);
    ya[4] = bfl(yau.z); ya[5] = bfh(yau.z); ya[6] = bfl(yau.w); ya[7] = bfh(yau.w);
    yb[0] = bfl(ybu.x); yb[1] = bfh(ybu.x); yb[2] = bfl(ybu.y); yb[3] = bfh(ybu.y);
    yb[4] = bfl(ybu.z); yb[5] = bfh(ybu.z); yb[6] = bfl(ybu.w); yb[7] = bfh(ybu.w);
    float d0 = 0.f, d1 = 0.f;
    float a0[8] = {0.f, 0.f, 0.f, 0.f, 0.f, 0.f, 0.f, 0.f};
    float a1[8] = {0.f, 0.f, 0.f, 0.f, 0.f, 0.f, 0.f, 0.f};
    for (int e = e0 + og; e < e1; e += 8) {
        int j = srcs[e];
        uint4 hb = *(const uint4*)&h1u[(size_t)j * 32 + 4 * sl];
        float h[8];
        h[0] = bfl(hb.x); h[1] = bfh(hb.x); h[2] = bfl(hb.y); h[3] = bfh(hb.y);
        h[4] = bfl(hb.z); h[5] = bfh(hb.z); h[6] = bfl(hb.w); h[7] = bfh(hb.w);
        float t0 = ya[0] * h[0] + ya[1] * h[1] + ya[2] * h[2] + ya[3] * h[3] +
                   ya[4] * h[4] + ya[5] * h[5] + ya[6] * h[6] + ya[7] * h[7];
        float t1 = yb[0] * h[0] + yb[1] * h[1] + yb[2] * h[2] + yb[3] * h[3] +
                   yb[4] * h[4] + yb[5] * h[5] + yb[6] * h[6] + yb[7] * h[7];
        t0 += __shfl_xor(t0, 1); t0 += __shfl_xor(t0, 2); t0 += __shfl_xor(t0, 4);
        t1 += __shfl_xor(t1, 1); t1 += __shfl_xor(t1, 2); t1 += __shfl_xor(t1, 4);
        float p0 = exp2f(t0 * SC);
        float p1 = exp2f(t1 * SC);
        d0 += p0;
        d1 += p1;
#pragma unroll
        for (int k = 0; k < 8; ++k) {
            a0[k] += p0 * h[k];
            a1[k] += p1 * h[k];
        }
    }
    // merge the 8 octets (plain sums)
#pragma unroll
    for (int mask = 8; mask <= 32; mask <<= 1) {
        d0 += __shfl_xor(d0, mask);
        d1 += __shfl_xor(d1, mask);
#pragma unroll
        for (int k = 0; k < 8; ++k) {
            a0[k] += __shfl_xor(a0[k], mask);
            a1[k] += __shfl_xor(a1[k], mask);
        }
    }
    if (og == 0) {
        float i0 = 1.f / fmaxf(d0, 1e-16f), i1 = 1.f / fmaxf(d1, 1e-16f);
        uint4 pa, pb;
        pa.x = f2bf(a0[0] * i0) | (f2bf(a0[1] * i0) << 16);
        pa.y = f2bf(a0[2] * i0) | (f2bf(a0[3] * i0) << 16);
        pa.z = f2bf(a0[4] * i0) | (f2bf(a0[5] * i0) << 16);
        pa.w = f2bf(a0[6] * i0) | (f2bf(a0[7] * i0) << 16);
        pb.x = f2bf(a1[0] * i1) | (f2bf(a1[1] * i1) << 16);
        pb.y = f2bf(a1[2] * i1) | (f2bf(a1[3] * i1) << 16);
        pb.z = f2bf(a1[4] * i1) | (f2bf(a1[5] * i1) << 16);
        pb.w = f2bf(a1[6] * i1) | (f2bf(a1[7] * i1) << 16);
        *(uint4*)&a01[(size_t)i * 64 + 4 * sl] = pa;
        *(uint4*)&a01[(size_t)i * 64 + 32 + 4 * sl] = pb;
        if (sl == 0) {
            float2 sg = {d0 > 0.f ? 1.f : 0.f, d1 > 0.f ? 1.f : 0.f};
            sig2[i] = sg;
        }
    }
}

// ---------------- epi2: out = relu([a0|a1|h1]@B192 + sigma*bv + bs) + LDS pool ----
__global__ __launch_bounds__(256) void epi2(
        const ushort* __restrict__ a01, const ushort* __restrict__ h1b,
        const ushort* __restrict__ B192, const float* __restrict__ bv,
        const float* __restrict__ bs, const float* __restrict__ sig2,
        const int* __restrict__ batch, unsigned* __restrict__ pool, int n) {
    __shared__ float po[16][128];
    __shared__ int pg[16];
    int node0 = blockIdx.x * 16;
    int w = threadIdx.x >> 6, l = threadIdx.x & 63;
    int arow = node0 + (l & 15);
    int arc = (arow < n) ? arow : (n - 1);
    int koff = (l >> 4) << 3;
    s16x8 af[6];
    af[0] = *(const s16x8*)&a01[(size_t)arc * 128 + 0 + koff];
    af[1] = *(const s16x8*)&a01[(size_t)arc * 128 + 32 + koff];
    af[2] = *(const s16x8*)&a01[(size_t)arc * 128 + 64 + koff];
    af[3] = *(const s16x8*)&a01[(size_t)arc * 128 + 96 + koff];
    af[4] = *(const s16x8*)&h1b[(size_t)arc * 64 + 0 + koff];
    af[5] = *(const s16x8*)&h1b[(size_t)arc * 64 + 32 + koff];
    if (threadIdx.x < 16)
        pg[threadIdx.x] = (node0 + threadIdx.x < n) ? batch[node0 + threadIdx.x] : -1;
    int cl = l & 15;
#pragma unroll
    for (int qq = 0; qq < 2; ++qq) {
        int ct = w * 2 + qq;
        f32x4 acc = {0.f, 0.f, 0.f, 0.f};
#pragma unroll
        for (int ks = 0; ks < 6; ++ks) {
            s16x8 b = *(const s16x8*)&B192[(size_t)(ct * 6 + ks) * 512 + l * 8];
            acc = __builtin_amdgcn_mfma_f32_16x16x32_bf16(af[ks], b, acc, 0, 0, 0);
        }
        int cg = ct * 16 + cl;
        int head = cg >> 6;
        float bbs = bs[cg], bbv = bv[cg];
#pragma unroll
        for (int r = 0; r < 4; ++r) {
            int row = ((l >> 4) << 2) + r;
            int node = node0 + row;
            float sg = (node < n) ? sig2[node * 2 + head] : 0.f;
            po[row][cg] = fmaxf(acc[r] + sg * bbv + bbs, 0.f);
        }
    }
    __syncthreads();
    int t = threadIdx.x;
    if (t < 128) {
        int curg = -1;
        float mx = 0.f;
        for (int r = 0; r < 16; ++r) {
            int g = pg[r];
            if (g < 0) continue;
            if (g != curg) {
                if (curg >= 0) atomicMax(&pool[(size_t)curg * 128 + t], __float_as_uint(mx));
                curg = g;
                mx = 0.f;
            }
            mx = fmaxf(mx, po[r][t]);
        }
        if (curg >= 0) atomicMax(&pool[(size_t)curg * 128 + t], __float_as_uint(mx));
    }
}

// ---------------- MLP head ----------------
__global__ void head_kernel(const unsigned* __restrict__ pbits,
                            const float* __restrict__ W1, const float* __restrict__ b1,
                            const float* __restrict__ W2, const float* __restrict__ b2,
                            const float* __restrict__ W3, const float* __restrict__ b3,
                            float* __restrict__ out, int G) {
    int g = blockIdx.x;
    int t = threadIdx.x;  // 128 threads
    __shared__ float ps[128], xl[32], y[128];
    ps[t] = __uint_as_float(pbits[g * 128 + t]);
    __syncthreads();
    if (t < 32) {
        float a = b1[t];
        for (int k = 0; k < 128; ++k) a += ps[k] * W1[k * 32 + t];
        a = fmaxf(a, 0.f);
        xl[t] = a;
        out[G * 40 + g * 32 + t] = a;
    }
    __syncthreads();
    {
        float a = b2[t];
        for (int k = 0; k < 32; ++k) a += xl[k] * W2[k * 128 + t];
        y[t] = fmaxf(a, 0.f);
    }
    __syncthreads();
    if (t < 40) {
        float a = b3[t];
        for (int k = 0; k < 128; ++k) a += y[k] * W3[k * 40 + t];  // W3 is (128,40)
        out[g * 40 + t] = a;
    }
}

extern "C" void kernel_launch(void* const* d_in, const int* in_sizes, int n_in,
                              void* d_out, int out_size, void* d_ws, size_t ws_size,
                              hipStream_t stream) {
    const float* x = (const float*)d_in[0];
    const int* eidx = (const int*)d_in[1];
    const int* batch = (const int*)d_in[2];
    const float *Wq1 = (const float*)d_in[3], *bq1 = (const float*)d_in[4];
    const float *Wk1 = (const float*)d_in[5], *bk1 = (const float*)d_in[6];
    const float *Wv1 = (const float*)d_in[7], *bv1 = (const float*)d_in[8];
    const float *Ws1 = (const float*)d_in[9], *bs1 = (const float*)d_in[10];
    const float *Wq2 = (const float*)d_in[11], *bq2 = (const float*)d_in[12];
    const float *Wk2 = (const float*)d_in[13], *bk2 = (const float*)d_in[14];
    const float *Wv2 = (const float*)d_in[15], *bv2 = (const float*)d_in[16];
    const float *Ws2 = (const float*)d_in[17], *bs2 = (const float*)d_in[18];
    const float *W1 = (const float*)d_in[19], *b1 = (const float*)d_in[20];
    const float *W2 = (const float*)d_in[21], *b2 = (const float*)d_in[22];
    const float *W3 = (const float*)d_in[23], *b3 = (const float*)d_in[24];
    (void)bk1; (void)bk2;  // bk terms cancel in softmax (constant per-dst shift)

    const int N = in_sizes[0] / 3;
    const int E = in_sizes[1] / 2;
    const int G = out_size / 72;  // 40 + 32 per graph
    const int* esrc = eidx;
    const int* edst = eidx + E;
    const int NB = (N + 255) / 256;
    const int POOLSZ = G * 128;
    const int PB = (POOLSZ + 255) / 256;

    char* w = (char*)d_ws;
    size_t o = 0;
    auto alloc = [&](size_t bytes) {
        void* p = w + o;
        o = (o + bytes + 255) & ~(size_t)255;
        return p;
    };
    float* c1buf = (float*)alloc(24 * 4);
    float* wcat = (float*)alloc(128 * 4);
    ushort* bfragY = (ushort*)alloc(16 * 512 * 2);
    ushort* B192 = (ushort*)alloc(48 * 512 * 2);
    unsigned* h1b = (unsigned*)alloc((size_t)N * 32 * 4);   // N x 64 bf16
    ushort* Ypb = (ushort*)alloc((size_t)N * 128 * 2);      // N x 128 bf16
    unsigned* a01 = (unsigned*)alloc((size_t)N * 64 * 4);   // N x 128 bf16
    float* sig2 = (float*)alloc((size_t)N * 2 * 4);
    int* deg = (int*)alloc((size_t)N * 4);
    int* off = (int*)alloc((size_t)(N + 1) * 4);
    int* cursor = (int*)alloc((size_t)N * 4);
    int* srcs = (int*)alloc((size_t)E * 4);
    unsigned* pool = (unsigned*)alloc((size_t)POOLSZ * 4);
    int* bsum = (int*)alloc(256 * 4);
    int* boff = (int*)alloc(256 * 4);
    (void)ws_size;

    // fused prep (weights -> c1/wcat/bfragY/B192) + zero deg + zero pool
    prep_all<<<45 + NB + PB, 256, 0, stream>>>(Wq1, bq1, Wk1, Wq2, bq2, Wk2, Wv2, Ws2,
                                               c1buf, wcat, bfragY, B192, deg, pool,
                                               N, NB, POOLSZ);

    // CSR by destination
    deg_kernel<<<(E + 255) / 256, 256, 0, stream>>>(edst, deg, E);
    scan_reduce<<<NB, 256, 0, stream>>>(deg, bsum, N);
    scan_blocks<<<1, 256, 0, stream>>>(bsum, boff, NB, off, N);
    scan_apply<<<NB, 256, 0, stream>>>(deg, boff, off, cursor, N);
    scatter_kernel<<<(E + 255) / 256, 256, 0, stream>>>(esrc, edst, cursor, srcs, E);

    // layer 1 (fused: scores via x^T M x, PV via (sum p x), V/skip/relu epilogue)
    attn1f<<<(N + 31) / 32, 256, 0, stream>>>(x, c1buf, Wv1, bv1, Ws1, bs1, off, srcs,
                                              h1b, N);

    // layer 2
    lin2Y<<<(N + 15) / 16, 256, 0, stream>>>((const ushort*)h1b, bfragY, wcat, Ypb, N);
    attn2_kernel<<<(N + 3) / 4, 256, 0, stream>>>(Ypb, h1b, off, srcs, a01,
                                                  (float2*)sig2, N);
    epi2<<<(N + 15) / 16, 256, 0, stream>>>((const ushort*)a01, (const ushort*)h1b, B192,
                                            bv2, bs2, sig2, batch, pool, N);

    // head
    head_kernel<<<G, 128, 0, stream>>>(pool, W1, b1, W2, b2, W3, b3, (float*)d_out, G);
}

// Round 17
// 185.369 us; speedup vs baseline: 1.3910x; 1.0694x over previous
//
#include <hip/hip_runtime.h>
#include <hip/hip_bf16.h>

typedef short s16x8 __attribute__((ext_vector_type(8)));   // 8 bf16 (4 VGPRs)
typedef float f32x4 __attribute__((ext_vector_type(4)));

#define LOG2E 1.4426950408889634f

__device__ __forceinline__ float bfl(unsigned w) { return __uint_as_float(w << 16); }
__device__ __forceinline__ float bfh(unsigned w) { return __uint_as_float(w & 0xffff0000u); }
__device__ __forceinline__ unsigned f2bf(float f) {
    unsigned u = __float_as_uint(f);
    return (u + 0x7fffu + ((u >> 16) & 1u)) >> 16;  // RNE, finite data
}

// ---------------- CSR build (XCD-partitioned by dst range) ----------------
// Round-16 profile: unpartitioned scatter wrote 52MB (line ping-pong across the
// 8 non-coherent per-XCD L2s: each node's 64B segment line was touched from all
// XCDs). Partitioning by dst-range with r = blockIdx&7 keeps each range's
// cursor/srcs lines on one XCD (round-robin dispatch heuristic; correctness
// does not depend on the mapping).
__global__ void deg_part(const int* __restrict__ dst, int* __restrict__ deg,
                         int E, int rsize) {
    int r = blockIdx.x & 7;
    int e = (blockIdx.x >> 3) * blockDim.x + threadIdx.x;
    if (e < E) {
        int d = dst[e];
        if (d / rsize == r) atomicAdd(&deg[d], 1);
    }
}

__global__ void scan_reduce(const int* __restrict__ deg, int* __restrict__ bsum, int n) {
    __shared__ int sh[256];
    int t = threadIdx.x;
    int i = blockIdx.x * 256 + t;
    sh[t] = (i < n) ? deg[i] : 0;
    __syncthreads();
    for (int s = 128; s > 0; s >>= 1) {
        if (t < s) sh[t] += sh[t + s];
        __syncthreads();
    }
    if (t == 0) bsum[blockIdx.x] = sh[0];
}

__global__ void scan_blocks(const int* __restrict__ bsum, int* __restrict__ boff,
                            int nb, int* __restrict__ off, int n) {
    __shared__ int sh[256];
    int t = threadIdx.x;
    int v = (t < nb) ? bsum[t] : 0;
    sh[t] = v;
    __syncthreads();
    for (int d = 1; d < 256; d <<= 1) {
        int x = (t >= d) ? sh[t - d] : 0;
        __syncthreads();
        sh[t] += x;
        __syncthreads();
    }
    if (t < nb) boff[t] = sh[t] - v;
    if (t == 255) off[n] = sh[255];
}

__global__ void scan_apply(const int* __restrict__ deg, const int* __restrict__ boff,
                           int* __restrict__ off, int* __restrict__ cursor, int n) {
    __shared__ int sh[256];
    int t = threadIdx.x;
    int i = blockIdx.x * 256 + t;
    int v = (i < n) ? deg[i] : 0;
    sh[t] = v;
    __syncthreads();
    for (int d = 1; d < 256; d <<= 1) {
        int x = (t >= d) ? sh[t - d] : 0;
        __syncthreads();
        sh[t] += x;
        __syncthreads();
    }
    int ex = sh[t] - v + boff[blockIdx.x];
    if (i < n) {
        off[i] = ex;
        cursor[i] = ex;
    }
}

__global__ void scatter_part(const int* __restrict__ src, const int* __restrict__ dst,
                             int* __restrict__ cursor, int* __restrict__ srcs,
                             int E, int rsize) {
    int r = blockIdx.x & 7;
    int e = (blockIdx.x >> 3) * blockDim.x + threadIdx.x;
    if (e < E) {
        int d = dst[e];
        if (d / rsize == r) {
            int p = atomicAdd(&cursor[d], 1);
            srcs[p] = src[e];
        }
    }
}

// ---------------- prep_all: fused weight preprocessing + buffer zeroing ----------
__global__ void prep_all(const float* __restrict__ Wq1, const float* __restrict__ bq1,
                         const float* __restrict__ Wk1,
                         const float* __restrict__ Wq2, const float* __restrict__ bq2,
                         const float* __restrict__ Wk2,
                         const float* __restrict__ Wv2, const float* __restrict__ Ws2,
                         float* __restrict__ c1, float* __restrict__ wcat,
                         ushort* __restrict__ bfragY, ushort* __restrict__ B192,
                         int* __restrict__ deg, unsigned* __restrict__ pool,
                         int n, int nbdeg, int poolsz) {
    int b = blockIdx.x, t = threadIdx.x;
    if (b == 0) {
        if (t < 18) {
            int h = t / 9, rr = t % 9, r = rr / 3, rp = rr % 3;
            float s = 0.f;
            for (int d = 0; d < 32; ++d)
                s += Wq1[r * 64 + h * 32 + d] * Wk1[rp * 64 + h * 32 + d];
            c1[t] = s;
        } else if (t < 24) {
            int u = t - 18, h = u / 3, rp = u % 3;
            float s = 0.f;
            for (int d = 0; d < 32; ++d)
                s += bq1[h * 32 + d] * Wk1[rp * 64 + h * 32 + d];
            c1[t] = s;
        } else if (t >= 64 && t < 192) {
            int cc = t - 64, h = cc >> 6, kp = cc & 63;
            float s = 0.f;
            for (int d = 0; d < 64; ++d)
                s += bq2[h * 64 + d] * Wk2[kp * 128 + h * 64 + d];
            wcat[cc] = s;
        }
    } else if (b < 33) {
        int idx = (b - 1) * 256 + t;  // 0..8191 = Mcat element (k, cc)
        int k = idx >> 7, cc = idx & 127, h = cc >> 6, kp = cc & 63;
        float s = 0.f;
        for (int d = 0; d < 64; ++d)
            s += Wq2[k * 128 + h * 64 + d] * Wk2[kp * 128 + h * 64 + d];
        int frag = ((cc >> 4) << 1) | (k >> 5);
        int l = (cc & 15) | (((k >> 3) & 3) << 4);
        bfragY[(size_t)frag * 512 + l * 8 + (k & 7)] = (ushort)f2bf(s);
    } else if (b < 45) {
        int tt = (b - 33) * 256 + t;  // 0..3071 (48 frags x 64 lanes)
        int frag = tt >> 6, l = tt & 63;
        int ct = frag / 6, ks = frag % 6;
        int c = ct * 16 + (l & 15);
        int kbase = ks * 32 + ((l >> 4) << 3);
#pragma unroll
        for (int e = 0; e < 8; ++e) {
            int k = kbase + e;
            float v;
            if (k < 64) v = (c < 64) ? Wv2[k * 128 + c] : 0.f;
            else if (k < 128) v = (c >= 64) ? Wv2[(k - 64) * 128 + c] : 0.f;
            else v = Ws2[(k - 128) * 128 + c];
            B192[(size_t)frag * 512 + l * 8 + e] = (ushort)f2bf(v);
        }
    } else if (b < 45 + nbdeg) {
        int i = (b - 45) * 256 + t;
        if (i < n) deg[i] = 0;
    } else {
        int i = (b - 45 - nbdeg) * 256 + t;
        if (i < poolsz) pool[i] = 0;
    }
}

// ---------------- attn1f: fused layer-1 attention (no-max softmax) ----------------
__global__ __launch_bounds__(256) void attn1f(
        const float* __restrict__ x, const float* __restrict__ c1,
        const float* __restrict__ Wv, const float* __restrict__ bv,
        const float* __restrict__ Ws, const float* __restrict__ bs,
        const int* __restrict__ off, const int* __restrict__ srcs,
        unsigned* __restrict__ h1b, int n) {
    int lane = threadIdx.x & 63;
    int g = lane >> 3, sl = lane & 7;
    int i = (blockIdx.x * (blockDim.x >> 6) + (threadIdx.x >> 6)) * 8 + g;
    bool act = i < n;
    int ic = act ? i : 0;
    float x0 = x[ic * 3], x1 = x[ic * 3 + 1], x2 = x[ic * 3 + 2];
    float y0[3], y1[3];
#pragma unroll
    for (int rp = 0; rp < 3; ++rp) {
        y0[rp] = x0 * c1[rp] + x1 * c1[3 + rp] + x2 * c1[6 + rp] + c1[18 + rp];
        y1[rp] = x0 * c1[9 + rp] + x1 * c1[12 + rp] + x2 * c1[15 + rp] + c1[21 + rp];
    }
    const float SC = 0.17677669529663688f * LOG2E;  // scale/sqrt(32) * log2(e)
    int e0 = act ? off[ic] : 0, e1 = act ? off[ic + 1] : 0;
    float d0 = 0.f, d1 = 0.f;
    float a0x = 0.f, a0y = 0.f, a0z = 0.f, a1x = 0.f, a1y = 0.f, a1z = 0.f;
    for (int e = e0 + sl; e < e1; e += 8) {
        int j = srcs[e];
        float xj0 = x[j * 3], xj1 = x[j * 3 + 1], xj2 = x[j * 3 + 2];
        float p0 = exp2f((y0[0] * xj0 + y0[1] * xj1 + y0[2] * xj2) * SC);
        float p1 = exp2f((y1[0] * xj0 + y1[1] * xj1 + y1[2] * xj2) * SC);
        d0 += p0; a0x += p0 * xj0; a0y += p0 * xj1; a0z += p0 * xj2;
        d1 += p1; a1x += p1 * xj0; a1y += p1 * xj1; a1z += p1 * xj2;
    }
#pragma unroll
    for (int mask = 1; mask <= 4; mask <<= 1) {
        d0 += __shfl_xor(d0, mask); d1 += __shfl_xor(d1, mask);
        a0x += __shfl_xor(a0x, mask); a0y += __shfl_xor(a0y, mask);
        a0z += __shfl_xor(a0z, mask); a1x += __shfl_xor(a1x, mask);
        a1y += __shfl_xor(a1y, mask); a1z += __shfl_xor(a1z, mask);
    }
    if (!act) return;
    int head = sl >> 2;
    float dh = head ? d1 : d0;
    float inv = 1.f / fmaxf(dh, 1e-16f);
    float sg = dh > 0.f ? 1.f : 0.f;
    float Ax = (head ? a1x : a0x) * inv;
    float Ay = (head ? a1y : a0y) * inv;
    float Az = (head ? a1z : a0z) * inv;
    unsigned pk[4];
#pragma unroll
    for (int u = 0; u < 4; ++u) {
        int c = sl * 8 + 2 * u;
        float2 wv0 = *(const float2*)&Wv[c], wv1 = *(const float2*)&Wv[64 + c],
               wv2 = *(const float2*)&Wv[128 + c];
        float2 ws0 = *(const float2*)&Ws[c], ws1 = *(const float2*)&Ws[64 + c],
               ws2 = *(const float2*)&Ws[128 + c];
        float2 bbv = *(const float2*)&bv[c];
        float2 bbs = *(const float2*)&bs[c];
        float v0 = Ax * wv0.x + Ay * wv1.x + Az * wv2.x + sg * bbv.x +
                   x0 * ws0.x + x1 * ws1.x + x2 * ws2.x + bbs.x;
        float v1 = Ax * wv0.y + Ay * wv1.y + Az * wv2.y + sg * bbv.y +
                   x0 * ws0.y + x1 * ws1.y + x2 * ws2.y + bbs.y;
        pk[u] = f2bf(fmaxf(v0, 0.f)) | (f2bf(fmaxf(v1, 0.f)) << 16);
    }
    uint4 pa = {pk[0], pk[1], pk[2], pk[3]};
    *(uint4*)&h1b[(size_t)i * 32 + sl * 4] = pa;
}

// ---------------- lin2Y: Y' = h1 @ Mcat + wcat (MFMA, N x 128 bf16) --------------
__global__ __launch_bounds__(256) void lin2Y(const ushort* __restrict__ h1b,
                                             const ushort* __restrict__ bfragY,
                                             const float* __restrict__ wcat,
                                             ushort* __restrict__ Ypb, int n) {
    int node0 = blockIdx.x * 16;
    int w = threadIdx.x >> 6, l = threadIdx.x & 63;
    int arow = node0 + (l & 15);
    if (arow >= n) arow = n - 1;
    s16x8 a0 = *(const s16x8*)&h1b[(size_t)arow * 64 + ((l >> 4) << 3)];
    s16x8 a1 = *(const s16x8*)&h1b[(size_t)arow * 64 + 32 + ((l >> 4) << 3)];
    int cl = l & 15;
#pragma unroll
    for (int qq = 0; qq < 2; ++qq) {
        int ct = w * 2 + qq;
        s16x8 b0 = *(const s16x8*)&bfragY[(size_t)(ct * 2 + 0) * 512 + l * 8];
        s16x8 b1 = *(const s16x8*)&bfragY[(size_t)(ct * 2 + 1) * 512 + l * 8];
        f32x4 acc = {0.f, 0.f, 0.f, 0.f};
        acc = __builtin_amdgcn_mfma_f32_16x16x32_bf16(a0, b0, acc, 0, 0, 0);
        acc = __builtin_amdgcn_mfma_f32_16x16x32_bf16(a1, b1, acc, 0, 0, 0);
        int cg = ct * 16 + cl;
        float bb = wcat[cg];
#pragma unroll
        for (int r = 0; r < 4; ++r) {
            int node = node0 + ((l >> 4) << 2) + r;
            if (node < n) Ypb[(size_t)node * 128 + cg] = (ushort)f2bf(acc[r] + bb);
        }
    }
}

// ---------------- attn2: fused no-max softmax over h1 gathers ---------------------
__global__ void attn2_kernel(const ushort* __restrict__ Ypb, const unsigned* __restrict__ h1u,
                             const int* __restrict__ off, const int* __restrict__ srcs,
                             unsigned* __restrict__ a01, float2* __restrict__ sig2, int n) {
    int i = blockIdx.x * (blockDim.x >> 6) + (threadIdx.x >> 6);
    int lane = threadIdx.x & 63;
    if (i >= n) return;
    int og = lane >> 3, sl = lane & 7;
    int e0 = off[i], e1 = off[i + 1];
    const float SC = 0.125f * LOG2E;  // 1/sqrt(64) * log2(e)
    uint4 yau = *(const uint4*)&Ypb[(size_t)i * 128 + 8 * sl];
    uint4 ybu = *(const uint4*)&Ypb[(size_t)i * 128 + 64 + 8 * sl];
    float ya[8], yb[8];
    ya[0] = bfl(yau.x); ya[1] = bfh(yau.x); ya[2] = bfl(yau.y); ya[3] = bfh(yau.y);
    ya[4] = bfl(yau.z); ya[5] = bfh(yau.z); ya[6] = bfl(yau.w); ya[7] = bfh(yau.w);
    yb[0] = bfl(ybu.x); yb[1] = bfh(ybu.x); yb[2] = bfl(ybu.y); yb[3] = bfh(ybu.y);
    yb[4] = bfl(ybu.z); yb[5] = bfh(ybu.z); yb[6] = bfl(ybu.w); yb[7] = bfh(ybu.w);
    float d0 = 0.f, d1 = 0.f;
    float a0[8] = {0.f, 0.f, 0.f, 0.f, 0.f, 0.f, 0.f, 0.f};
    float a1[8] = {0.f, 0.f, 0.f, 0.f, 0.f, 0.f, 0.f, 0.f};
    for (int e = e0 + og; e < e1; e += 8) {
        int j = srcs[e];
        uint4 hb = *(const uint4*)&h1u[(size_t)j * 32 + 4 * sl];
        float h[8];
        h[0] = bfl(hb.x); h[1] = bfh(hb.x); h[2] = bfl(hb.y); h[3] = bfh(hb.y);
        h[4] = bfl(hb.z); h[5] = bfh(hb.z); h[6] = bfl(hb.w); h[7] = bfh(hb.w);
        float t0 = ya[0] * h[0] + ya[1] * h[1] + ya[2] * h[2] + ya[3] * h[3] +
                   ya[4] * h[4] + ya[5] * h[5] + ya[6] * h[6] + ya[7] * h[7];
        float t1 = yb[0] * h[0] + yb[1] * h[1] + yb[2] * h[2] + yb[3] * h[3] +
                   yb[4] * h[4] + yb[5] * h[5] + yb[6] * h[6] + yb[7] * h[7];
        t0 += __shfl_xor(t0, 1); t0 += __shfl_xor(t0, 2); t0 += __shfl_xor(t0, 4);
        t1 += __shfl_xor(t1, 1); t1 += __shfl_xor(t1, 2); t1 += __shfl_xor(t1, 4);
        float p0 = exp2f(t0 * SC);
        float p1 = exp2f(t1 * SC);
        d0 += p0;
        d1 += p1;
#pragma unroll
        for (int k = 0; k < 8; ++k) {
            a0[k] += p0 * h[k];
            a1[k] += p1 * h[k];
        }
    }
    // merge the 8 octets (plain sums)
#pragma unroll
    for (int mask = 8; mask <= 32; mask <<= 1) {
        d0 += __shfl_xor(d0, mask);
        d1 += __shfl_xor(d1, mask);
#pragma unroll
        for (int k = 0; k < 8; ++k) {
            a0[k] += __shfl_xor(a0[k], mask);
            a1[k] += __shfl_xor(a1[k], mask);
        }
    }
    if (og == 0) {
        float i0 = 1.f / fmaxf(d0, 1e-16f), i1 = 1.f / fmaxf(d1, 1e-16f);
        uint4 pa, pb;
        pa.x = f2bf(a0[0] * i0) | (f2bf(a0[1] * i0) << 16);
        pa.y = f2bf(a0[2] * i0) | (f2bf(a0[3] * i0) << 16);
        pa.z = f2bf(a0[4] * i0) | (f2bf(a0[5] * i0) << 16);
        pa.w = f2bf(a0[6] * i0) | (f2bf(a0[7] * i0) << 16);
        pb.x = f2bf(a1[0] * i1) | (f2bf(a1[1] * i1) << 16);
        pb.y = f2bf(a1[2] * i1) | (f2bf(a1[3] * i1) << 16);
        pb.z = f2bf(a1[4] * i1) | (f2bf(a1[5] * i1) << 16);
        pb.w = f2bf(a1[6] * i1) | (f2bf(a1[7] * i1) << 16);
        *(uint4*)&a01[(size_t)i * 64 + 4 * sl] = pa;
        *(uint4*)&a01[(size_t)i * 64 + 32 + 4 * sl] = pb;
        if (sl == 0) {
            float2 sg = {d0 > 0.f ? 1.f : 0.f, d1 > 0.f ? 1.f : 0.f};
            sig2[i] = sg;
        }
    }
}

// ---------------- epi2: out = relu([a0|a1|h1]@B192 + sigma*bv + bs) + LDS pool ----
__global__ __launch_bounds__(256) void epi2(
        const ushort* __restrict__ a01, const ushort* __restrict__ h1b,
        const ushort* __restrict__ B192, const float* __restrict__ bv,
        const float* __restrict__ bs, const float* __restrict__ sig2,
        const int* __restrict__ batch, unsigned* __restrict__ pool, int n) {
    __shared__ float po[16][128];
    __shared__ int pg[16];
    int node0 = blockIdx.x * 16;
    int w = threadIdx.x >> 6, l = threadIdx.x & 63;
    int arow = node0 + (l & 15);
    int arc = (arow < n) ? arow : (n - 1);
    int koff = (l >> 4) << 3;
    s16x8 af[6];
    af[0] = *(const s16x8*)&a01[(size_t)arc * 128 + 0 + koff];
    af[1] = *(const s16x8*)&a01[(size_t)arc * 128 + 32 + koff];
    af[2] = *(const s16x8*)&a01[(size_t)arc * 128 + 64 + koff];
    af[3] = *(const s16x8*)&a01[(size_t)arc * 128 + 96 + koff];
    af[4] = *(const s16x8*)&h1b[(size_t)arc * 64 + 0 + koff];
    af[5] = *(const s16x8*)&h1b[(size_t)arc * 64 + 32 + koff];
    if (threadIdx.x < 16)
        pg[threadIdx.x] = (node0 + threadIdx.x < n) ? batch[node0 + threadIdx.x] : -1;
    int cl = l & 15;
#pragma unroll
    for (int qq = 0; qq < 2; ++qq) {
        int ct = w * 2 + qq;
        f32x4 acc = {0.f, 0.f, 0.f, 0.f};
#pragma unroll
        for (int ks = 0; ks < 6; ++ks) {
            s16x8 b = *(const s16x8*)&B192[(size_t)(ct * 6 + ks) * 512 + l * 8];
            acc = __builtin_amdgcn_mfma_f32_16x16x32_bf16(af[ks], b, acc, 0, 0, 0);
        }
        int cg = ct * 16 + cl;
        int head = cg >> 6;
        float bbs = bs[cg], bbv = bv[cg];
#pragma unroll
        for (int r = 0; r < 4; ++r) {
            int row = ((l >> 4) << 2) + r;
            int node = node0 + row;
            float sg = (node < n) ? sig2[node * 2 + head] : 0.f;
            po[row][cg] = fmaxf(acc[r] + sg * bbv + bbs, 0.f);
        }
    }
    __syncthreads();
    int t = threadIdx.x;
    if (t < 128) {
        int curg = -1;
        float mx = 0.f;
        for (int r = 0; r < 16; ++r) {
            int g = pg[r];
            if (g < 0) continue;
            if (g != curg) {
                if (curg >= 0) atomicMax(&pool[(size_t)curg * 128 + t], __float_as_uint(mx));
                curg = g;
                mx = 0.f;
            }
            mx = fmaxf(mx, po[r][t]);
        }
        if (curg >= 0) atomicMax(&pool[(size_t)curg * 128 + t], __float_as_uint(mx));
    }
}

// ---------------- MLP head ----------------
__global__ void head_kernel(const unsigned* __restrict__ pbits,
                            const float* __restrict__ W1, const float* __restrict__ b1,
                            const float* __restrict__ W2, const float* __restrict__ b2,
                            const float* __restrict__ W3, const float* __restrict__ b3,
                            float* __restrict__ out, int G) {
    int g = blockIdx.x;
    int t = threadIdx.x;  // 128 threads
    __shared__ float ps[128], xl[32], y[128];
    ps[t] = __uint_as_float(pbits[g * 128 + t]);
    __syncthreads();
    if (t < 32) {
        float a = b1[t];
        for (int k = 0; k < 128; ++k) a += ps[k] * W1[k * 32 + t];
        a = fmaxf(a, 0.f);
        xl[t] = a;
        out[G * 40 + g * 32 + t] = a;
    }
    __syncthreads();
    {
        float a = b2[t];
        for (int k = 0; k < 32; ++k) a += xl[k] * W2[k * 128 + t];
        y[t] = fmaxf(a, 0.f);
    }
    __syncthreads();
    if (t < 40) {
        float a = b3[t];
        for (int k = 0; k < 128; ++k) a += y[k] * W3[k * 40 + t];  // W3 is (128,40)
        out[g * 40 + t] = a;
    }
}

extern "C" void kernel_launch(void* const* d_in, const int* in_sizes, int n_in,
                              void* d_out, int out_size, void* d_ws, size_t ws_size,
                              hipStream_t stream) {
    const float* x = (const float*)d_in[0];
    const int* eidx = (const int*)d_in[1];
    const int* batch = (const int*)d_in[2];
    const float *Wq1 = (const float*)d_in[3], *bq1 = (const float*)d_in[4];
    const float *Wk1 = (const float*)d_in[5], *bk1 = (const float*)d_in[6];
    const float *Wv1 = (const float*)d_in[7], *bv1 = (const float*)d_in[8];
    const float *Ws1 = (const float*)d_in[9], *bs1 = (const float*)d_in[10];
    const float *Wq2 = (const float*)d_in[11], *bq2 = (const float*)d_in[12];
    const float *Wk2 = (const float*)d_in[13], *bk2 = (const float*)d_in[14];
    const float *Wv2 = (const float*)d_in[15], *bv2 = (const float*)d_in[16];
    const float *Ws2 = (const float*)d_in[17], *bs2 = (const float*)d_in[18];
    const float *W1 = (const float*)d_in[19], *b1 = (const float*)d_in[20];
    const float *W2 = (const float*)d_in[21], *b2 = (const float*)d_in[22];
    const float *W3 = (const float*)d_in[23], *b3 = (const float*)d_in[24];
    (void)bk1; (void)bk2;  // bk terms cancel in softmax (constant per-dst shift)

    const int N = in_sizes[0] / 3;
    const int E = in_sizes[1] / 2;
    const int G = out_size / 72;  // 40 + 32 per graph
    const int* esrc = eidx;
    const int* edst = eidx + E;
    const int NB = (N + 255) / 256;
    const int EB = (E + 255) / 256;
    const int POOLSZ = G * 128;
    const int PB = (POOLSZ + 255) / 256;
    const int RSIZE = (N + 7) / 8;  // dst-range size per XCD partition

    char* w = (char*)d_ws;
    size_t o = 0;
    auto alloc = [&](size_t bytes) {
        void* p = w + o;
        o = (o + bytes + 255) & ~(size_t)255;
        return p;
    };
    float* c1buf = (float*)alloc(24 * 4);
    float* wcat = (float*)alloc(128 * 4);
    ushort* bfragY = (ushort*)alloc(16 * 512 * 2);
    ushort* B192 = (ushort*)alloc(48 * 512 * 2);
    unsigned* h1b = (unsigned*)alloc((size_t)N * 32 * 4);   // N x 64 bf16
    ushort* Ypb = (ushort*)alloc((size_t)N * 128 * 2);      // N x 128 bf16
    unsigned* a01 = (unsigned*)alloc((size_t)N * 64 * 4);   // N x 128 bf16
    float* sig2 = (float*)alloc((size_t)N * 2 * 4);
    int* deg = (int*)alloc((size_t)N * 4);
    int* off = (int*)alloc((size_t)(N + 1) * 4);
    int* cursor = (int*)alloc((size_t)N * 4);
    int* srcs = (int*)alloc((size_t)E * 4);
    unsigned* pool = (unsigned*)alloc((size_t)POOLSZ * 4);
    int* bsum = (int*)alloc(256 * 4);
    int* boff = (int*)alloc(256 * 4);
    (void)ws_size;

    // fused prep (weights -> c1/wcat/bfragY/B192) + zero deg + zero pool
    prep_all<<<45 + NB + PB, 256, 0, stream>>>(Wq1, bq1, Wk1, Wq2, bq2, Wk2, Wv2, Ws2,
                                               c1buf, wcat, bfragY, B192, deg, pool,
                                               N, NB, POOLSZ);

    // CSR by destination (XCD-partitioned atomics/writes)
    deg_part<<<8 * EB, 256, 0, stream>>>(edst, deg, E, RSIZE);
    scan_reduce<<<NB, 256, 0, stream>>>(deg, bsum, N);
    scan_blocks<<<1, 256, 0, stream>>>(bsum, boff, NB, off, N);
    scan_apply<<<NB, 256, 0, stream>>>(deg, boff, off, cursor, N);
    scatter_part<<<8 * EB, 256, 0, stream>>>(esrc, edst, cursor, srcs, E, RSIZE);

    // layer 1 (fused: scores via x^T M x, PV via (sum p x), V/skip/relu epilogue)
    attn1f<<<(N + 31) / 32, 256, 0, stream>>>(x, c1buf, Wv1, bv1, Ws1, bs1, off, srcs,
                                              h1b, N);

    // layer 2
    lin2Y<<<(N + 15) / 16, 256, 0, stream>>>((const ushort*)h1b, bfragY, wcat, Ypb, N);
    attn2_kernel<<<(N + 3) / 4, 256, 0, stream>>>(Ypb, h1b, off, srcs, a01,
                                                  (float2*)sig2, N);
    epi2<<<(N + 15) / 16, 256, 0, stream>>>((const ushort*)a01, (const ushort*)h1b, B192,
                                            bv2, bs2, sig2, batch, pool, N);

    // head
    head_kernel<<<G, 128, 0, stream>>>(pool, W1, b1, W2, b2, W3, b3, (float*)d_out, G);
}

// Round 18
// 181.152 us; speedup vs baseline: 1.4233x; 1.0233x over previous
//
#include <hip/hip_runtime.h>
#include <hip/hip_bf16.h>

typedef short s16x8 __attribute__((ext_vector_type(8)));   // 8 bf16 (4 VGPRs)
typedef float f32x4 __attribute__((ext_vector_type(4)));

#define LOG2E 1.4426950408889634f

__device__ __forceinline__ float bfl(unsigned w) { return __uint_as_float(w << 16); }
__device__ __forceinline__ float bfh(unsigned w) { return __uint_as_float(w & 0xffff0000u); }
__device__ __forceinline__ unsigned f2bf(float f) {
    unsigned u = __float_as_uint(f);
    return (u + 0x7fffu + ((u >> 16) & 1u)) >> 16;  // RNE, finite data
}

// ---------------- CSR build (XCD-partitioned by dst range) ----------------
__global__ void deg_part(const int* __restrict__ dst, int* __restrict__ deg,
                         int E, int rsize) {
    int r = blockIdx.x & 7;
    int e = (blockIdx.x >> 3) * blockDim.x + threadIdx.x;
    if (e < E) {
        int d = dst[e];
        if (d / rsize == r) atomicAdd(&deg[d], 1);
    }
}

__global__ void scan_reduce(const int* __restrict__ deg, int* __restrict__ bsum, int n) {
    __shared__ int sh[256];
    int t = threadIdx.x;
    int i = blockIdx.x * 256 + t;
    sh[t] = (i < n) ? deg[i] : 0;
    __syncthreads();
    for (int s = 128; s > 0; s >>= 1) {
        if (t < s) sh[t] += sh[t + s];
        __syncthreads();
    }
    if (t == 0) bsum[blockIdx.x] = sh[0];
}

// scan_apply computes its own block offset (tree-reduce over bsum[k<b]) — the
// former scan_blocks 1-block kernel is folded in; off[n] = E (total degree).
__global__ void scan_apply(const int* __restrict__ deg, const int* __restrict__ bsum,
                           int* __restrict__ off, int* __restrict__ cursor,
                           int n, int nb, int Etot) {
    __shared__ int sh[256], sb[256];
    int t = threadIdx.x;
    int b = blockIdx.x;
    sb[t] = (t < nb && t < b) ? bsum[t] : 0;
    int i = b * 256 + t;
    int v = (i < n) ? deg[i] : 0;
    sh[t] = v;
    __syncthreads();
    for (int s = 128; s > 0; s >>= 1) {
        if (t < s) sb[t] += sb[t + s];
        __syncthreads();
    }
    int boffb = sb[0];
    __syncthreads();
    for (int d = 1; d < 256; d <<= 1) {
        int x = (t >= d) ? sh[t - d] : 0;
        __syncthreads();
        sh[t] += x;
        __syncthreads();
    }
    int ex = sh[t] - v + boffb;
    if (i < n) {
        off[i] = ex;
        cursor[i] = ex;
    }
    if (b == 0 && t == 0) off[n] = Etot;
}

__global__ void scatter_part(const int* __restrict__ src, const int* __restrict__ dst,
                             int* __restrict__ cursor, int* __restrict__ srcs,
                             int E, int rsize) {
    int r = blockIdx.x & 7;
    int e = (blockIdx.x >> 3) * blockDim.x + threadIdx.x;
    if (e < E) {
        int d = dst[e];
        if (d / rsize == r) {
            int p = atomicAdd(&cursor[d], 1);
            srcs[p] = src[e];
        }
    }
}

// ---------------- prep_all: fused weight preprocessing + buffer zeroing ----------
__global__ void prep_all(const float* __restrict__ Wq1, const float* __restrict__ bq1,
                         const float* __restrict__ Wk1,
                         const float* __restrict__ Wq2, const float* __restrict__ bq2,
                         const float* __restrict__ Wk2,
                         const float* __restrict__ Wv2, const float* __restrict__ Ws2,
                         float* __restrict__ c1, float* __restrict__ wcat,
                         ushort* __restrict__ bfragY, ushort* __restrict__ B192,
                         int* __restrict__ deg, unsigned* __restrict__ pool,
                         int n, int nbdeg, int poolsz) {
    int b = blockIdx.x, t = threadIdx.x;
    if (b == 0) {
        if (t < 18) {
            int h = t / 9, rr = t % 9, r = rr / 3, rp = rr % 3;
            float s = 0.f;
            for (int d = 0; d < 32; ++d)
                s += Wq1[r * 64 + h * 32 + d] * Wk1[rp * 64 + h * 32 + d];
            c1[t] = s;
        } else if (t < 24) {
            int u = t - 18, h = u / 3, rp = u % 3;
            float s = 0.f;
            for (int d = 0; d < 32; ++d)
                s += bq1[h * 32 + d] * Wk1[rp * 64 + h * 32 + d];
            c1[t] = s;
        } else if (t >= 64 && t < 192) {
            int cc = t - 64, h = cc >> 6, kp = cc & 63;
            float s = 0.f;
            for (int d = 0; d < 64; ++d)
                s += bq2[h * 64 + d] * Wk2[kp * 128 + h * 64 + d];
            wcat[cc] = s;
        }
    } else if (b < 33) {
        int idx = (b - 1) * 256 + t;  // 0..8191 = Mcat element (k, cc)
        int k = idx >> 7, cc = idx & 127, h = cc >> 6, kp = cc & 63;
        float s = 0.f;
        for (int d = 0; d < 64; ++d)
            s += Wq2[k * 128 + h * 64 + d] * Wk2[kp * 128 + h * 64 + d];
        int frag = ((cc >> 4) << 1) | (k >> 5);
        int l = (cc & 15) | (((k >> 3) & 3) << 4);
        bfragY[(size_t)frag * 512 + l * 8 + (k & 7)] = (ushort)f2bf(s);
    } else if (b < 45) {
        int tt = (b - 33) * 256 + t;  // 0..3071 (48 frags x 64 lanes)
        int frag = tt >> 6, l = tt & 63;
        int ct = frag / 6, ks = frag % 6;
        int c = ct * 16 + (l & 15);
        int kbase = ks * 32 + ((l >> 4) << 3);
#pragma unroll
        for (int e = 0; e < 8; ++e) {
            int k = kbase + e;
            float v;
            if (k < 64) v = (c < 64) ? Wv2[k * 128 + c] : 0.f;
            else if (k < 128) v = (c >= 64) ? Wv2[(k - 64) * 128 + c] : 0.f;
            else v = Ws2[(k - 128) * 128 + c];
            B192[(size_t)frag * 512 + l * 8 + e] = (ushort)f2bf(v);
        }
    } else if (b < 45 + nbdeg) {
        int i = (b - 45) * 256 + t;
        if (i < n) deg[i] = 0;
    } else {
        int i = (b - 45 - nbdeg) * 256 + t;
        if (i < poolsz) pool[i] = 0;
    }
}

// ---------------- attn1f: fused layer-1 attention (no-max softmax) ----------------
__global__ __launch_bounds__(256) void attn1f(
        const float* __restrict__ x, const float* __restrict__ c1,
        const float* __restrict__ Wv, const float* __restrict__ bv,
        const float* __restrict__ Ws, const float* __restrict__ bs,
        const int* __restrict__ off, const int* __restrict__ srcs,
        unsigned* __restrict__ h1b, int n) {
    int lane = threadIdx.x & 63;
    int g = lane >> 3, sl = lane & 7;
    int i = (blockIdx.x * (blockDim.x >> 6) + (threadIdx.x >> 6)) * 8 + g;
    bool act = i < n;
    int ic = act ? i : 0;
    float x0 = x[ic * 3], x1 = x[ic * 3 + 1], x2 = x[ic * 3 + 2];
    float y0[3], y1[3];
#pragma unroll
    for (int rp = 0; rp < 3; ++rp) {
        y0[rp] = x0 * c1[rp] + x1 * c1[3 + rp] + x2 * c1[6 + rp] + c1[18 + rp];
        y1[rp] = x0 * c1[9 + rp] + x1 * c1[12 + rp] + x2 * c1[15 + rp] + c1[21 + rp];
    }
    const float SC = 0.17677669529663688f * LOG2E;  // scale/sqrt(32) * log2(e)
    int e0 = act ? off[ic] : 0, e1 = act ? off[ic + 1] : 0;
    float d0 = 0.f, d1 = 0.f;
    float a0x = 0.f, a0y = 0.f, a0z = 0.f, a1x = 0.f, a1y = 0.f, a1z = 0.f;
    for (int e = e0 + sl; e < e1; e += 8) {
        int j = srcs[e];
        float xj0 = x[j * 3], xj1 = x[j * 3 + 1], xj2 = x[j * 3 + 2];
        float p0 = exp2f((y0[0] * xj0 + y0[1] * xj1 + y0[2] * xj2) * SC);
        float p1 = exp2f((y1[0] * xj0 + y1[1] * xj1 + y1[2] * xj2) * SC);
        d0 += p0; a0x += p0 * xj0; a0y += p0 * xj1; a0z += p0 * xj2;
        d1 += p1; a1x += p1 * xj0; a1y += p1 * xj1; a1z += p1 * xj2;
    }
#pragma unroll
    for (int mask = 1; mask <= 4; mask <<= 1) {
        d0 += __shfl_xor(d0, mask); d1 += __shfl_xor(d1, mask);
        a0x += __shfl_xor(a0x, mask); a0y += __shfl_xor(a0y, mask);
        a0z += __shfl_xor(a0z, mask); a1x += __shfl_xor(a1x, mask);
        a1y += __shfl_xor(a1y, mask); a1z += __shfl_xor(a1z, mask);
    }
    if (!act) return;
    int head = sl >> 2;
    float dh = head ? d1 : d0;
    float inv = 1.f / fmaxf(dh, 1e-16f);
    float sg = dh > 0.f ? 1.f : 0.f;
    float Ax = (head ? a1x : a0x) * inv;
    float Ay = (head ? a1y : a0y) * inv;
    float Az = (head ? a1z : a0z) * inv;
    unsigned pk[4];
#pragma unroll
    for (int u = 0; u < 4; ++u) {
        int c = sl * 8 + 2 * u;
        float2 wv0 = *(const float2*)&Wv[c], wv1 = *(const float2*)&Wv[64 + c],
               wv2 = *(const float2*)&Wv[128 + c];
        float2 ws0 = *(const float2*)&Ws[c], ws1 = *(const float2*)&Ws[64 + c],
               ws2 = *(const float2*)&Ws[128 + c];
        float2 bbv = *(const float2*)&bv[c];
        float2 bbs = *(const float2*)&bs[c];
        float v0 = Ax * wv0.x + Ay * wv1.x + Az * wv2.x + sg * bbv.x +
                   x0 * ws0.x + x1 * ws1.x + x2 * ws2.x + bbs.x;
        float v1 = Ax * wv0.y + Ay * wv1.y + Az * wv2.y + sg * bbv.y +
                   x0 * ws0.y + x1 * ws1.y + x2 * ws2.y + bbs.y;
        pk[u] = f2bf(fmaxf(v0, 0.f)) | (f2bf(fmaxf(v1, 0.f)) << 16);
    }
    uint4 pa = {pk[0], pk[1], pk[2], pk[3]};
    *(uint4*)&h1b[(size_t)i * 32 + sl * 4] = pa;
}

// ---------------- lin2Y: Y' = h1 @ Mcat + wcat (MFMA, N x 128 bf16) --------------
__global__ __launch_bounds__(256) void lin2Y(const ushort* __restrict__ h1b,
                                             const ushort* __restrict__ bfragY,
                                             const float* __restrict__ wcat,
                                             ushort* __restrict__ Ypb, int n) {
    int node0 = blockIdx.x * 16;
    int w = threadIdx.x >> 6, l = threadIdx.x & 63;
    int arow = node0 + (l & 15);
    if (arow >= n) arow = n - 1;
    s16x8 a0 = *(const s16x8*)&h1b[(size_t)arow * 64 + ((l >> 4) << 3)];
    s16x8 a1 = *(const s16x8*)&h1b[(size_t)arow * 64 + 32 + ((l >> 4) << 3)];
    int cl = l & 15;
#pragma unroll
    for (int qq = 0; qq < 2; ++qq) {
        int ct = w * 2 + qq;
        s16x8 b0 = *(const s16x8*)&bfragY[(size_t)(ct * 2 + 0) * 512 + l * 8];
        s16x8 b1 = *(const s16x8*)&bfragY[(size_t)(ct * 2 + 1) * 512 + l * 8];
        f32x4 acc = {0.f, 0.f, 0.f, 0.f};
        acc = __builtin_amdgcn_mfma_f32_16x16x32_bf16(a0, b0, acc, 0, 0, 0);
        acc = __builtin_amdgcn_mfma_f32_16x16x32_bf16(a1, b1, acc, 0, 0, 0);
        int cg = ct * 16 + cl;
        float bb = wcat[cg];
#pragma unroll
        for (int r = 0; r < 4; ++r) {
            int node = node0 + ((l >> 4) << 2) + r;
            if (node < n) Ypb[(size_t)node * 128 + cg] = (ushort)f2bf(acc[r] + bb);
        }
    }
}

// ---------------- attn2: no-max softmax, 4 groups x 16 lanes --------------------
// Group qd=lane>>4 takes every-4th edge; lane sl=lane&15 owns channels 4sl..4sl+3
// (uint2 = 4 bf16; 16 lanes still read the full 128B h1 row coalesced).
// Merge = 2 rounds x 10 values (was 3 x 18 with the 8-octet split — merge-bound).
__global__ __launch_bounds__(256) void attn2_kernel(
        const ushort* __restrict__ Ypb, const unsigned* __restrict__ h1u,
        const int* __restrict__ off, const int* __restrict__ srcs,
        unsigned* __restrict__ a01, float2* __restrict__ sig2, int n) {
    int i = blockIdx.x * (blockDim.x >> 6) + (threadIdx.x >> 6);
    int lane = threadIdx.x & 63;
    if (i >= n) return;
    int qd = lane >> 4, sl = lane & 15;
    int e0 = off[i], e1 = off[i + 1];
    const float SC = 0.125f * LOG2E;  // 1/sqrt(64) * log2(e)
    uint2 yau = *(const uint2*)&Ypb[(size_t)i * 128 + 4 * sl];
    uint2 ybu = *(const uint2*)&Ypb[(size_t)i * 128 + 64 + 4 * sl];
    float ya[4], yb[4];
    ya[0] = bfl(yau.x); ya[1] = bfh(yau.x); ya[2] = bfl(yau.y); ya[3] = bfh(yau.y);
    yb[0] = bfl(ybu.x); yb[1] = bfh(ybu.x); yb[2] = bfl(ybu.y); yb[3] = bfh(ybu.y);
    float d0 = 0.f, d1 = 0.f;
    float a0[4] = {0.f, 0.f, 0.f, 0.f};
    float a1[4] = {0.f, 0.f, 0.f, 0.f};
    for (int e = e0 + qd; e < e1; e += 4) {
        int j = srcs[e];
        uint2 hb = *(const uint2*)&h1u[(size_t)j * 32 + 2 * sl];
        float h[4];
        h[0] = bfl(hb.x); h[1] = bfh(hb.x); h[2] = bfl(hb.y); h[3] = bfh(hb.y);
        float t0 = ya[0] * h[0] + ya[1] * h[1] + ya[2] * h[2] + ya[3] * h[3];
        float t1 = yb[0] * h[0] + yb[1] * h[1] + yb[2] * h[2] + yb[3] * h[3];
        t0 += __shfl_xor(t0, 1); t0 += __shfl_xor(t0, 2);
        t0 += __shfl_xor(t0, 4); t0 += __shfl_xor(t0, 8);
        t1 += __shfl_xor(t1, 1); t1 += __shfl_xor(t1, 2);
        t1 += __shfl_xor(t1, 4); t1 += __shfl_xor(t1, 8);
        float p0 = exp2f(t0 * SC);
        float p1 = exp2f(t1 * SC);
        d0 += p0;
        d1 += p1;
#pragma unroll
        for (int k = 0; k < 4; ++k) {
            a0[k] += p0 * h[k];
            a1[k] += p1 * h[k];
        }
    }
    // merge the 4 groups (plain sums, masks 16/32; 10 live values)
#pragma unroll
    for (int mask = 16; mask <= 32; mask <<= 1) {
        d0 += __shfl_xor(d0, mask);
        d1 += __shfl_xor(d1, mask);
#pragma unroll
        for (int k = 0; k < 4; ++k) {
            a0[k] += __shfl_xor(a0[k], mask);
            a1[k] += __shfl_xor(a1[k], mask);
        }
    }
    if (qd == 0) {
        float i0 = 1.f / fmaxf(d0, 1e-16f), i1 = 1.f / fmaxf(d1, 1e-16f);
        uint2 pa, pb;
        pa.x = f2bf(a0[0] * i0) | (f2bf(a0[1] * i0) << 16);
        pa.y = f2bf(a0[2] * i0) | (f2bf(a0[3] * i0) << 16);
        pb.x = f2bf(a1[0] * i1) | (f2bf(a1[1] * i1) << 16);
        pb.y = f2bf(a1[2] * i1) | (f2bf(a1[3] * i1) << 16);
        *(uint2*)&a01[(size_t)i * 64 + 2 * sl] = pa;
        *(uint2*)&a01[(size_t)i * 64 + 32 + 2 * sl] = pb;
        if (sl == 0) {
            float2 sg = {d0 > 0.f ? 1.f : 0.f, d1 > 0.f ? 1.f : 0.f};
            sig2[i] = sg;
        }
    }
}

// ---------------- epi2: out = relu([a0|a1|h1]@B192 + sigma*bv + bs) + LDS pool ----
__global__ __launch_bounds__(256) void epi2(
        const ushort* __restrict__ a01, const ushort* __restrict__ h1b,
        const ushort* __restrict__ B192, const float* __restrict__ bv,
        const float* __restrict__ bs, const float* __restrict__ sig2,
        const int* __restrict__ batch, unsigned* __restrict__ pool, int n) {
    __shared__ float po[16][128];
    __shared__ int pg[16];
    int node0 = blockIdx.x * 16;
    int w = threadIdx.x >> 6, l = threadIdx.x & 63;
    int arow = node0 + (l & 15);
    int arc = (arow < n) ? arow : (n - 1);
    int koff = (l >> 4) << 3;
    s16x8 af[6];
    af[0] = *(const s16x8*)&a01[(size_t)arc * 128 + 0 + koff];
    af[1] = *(const s16x8*)&a01[(size_t)arc * 128 + 32 + koff];
    af[2] = *(const s16x8*)&a01[(size_t)arc * 128 + 64 + koff];
    af[3] = *(const s16x8*)&a01[(size_t)arc * 128 + 96 + koff];
    af[4] = *(const s16x8*)&h1b[(size_t)arc * 64 + 0 + koff];
    af[5] = *(const s16x8*)&h1b[(size_t)arc * 64 + 32 + koff];
    if (threadIdx.x < 16)
        pg[threadIdx.x] = (node0 + threadIdx.x < n) ? batch[node0 + threadIdx.x] : -1;
    int cl = l & 15;
#pragma unroll
    for (int qq = 0; qq < 2; ++qq) {
        int ct = w * 2 + qq;
        f32x4 acc = {0.f, 0.f, 0.f, 0.f};
#pragma unroll
        for (int ks = 0; ks < 6; ++ks) {
            s16x8 b = *(const s16x8*)&B192[(size_t)(ct * 6 + ks) * 512 + l * 8];
            acc = __builtin_amdgcn_mfma_f32_16x16x32_bf16(af[ks], b, acc, 0, 0, 0);
        }
        int cg = ct * 16 + cl;
        int head = cg >> 6;
        float bbs = bs[cg], bbv = bv[cg];
#pragma unroll
        for (int r = 0; r < 4; ++r) {
            int row = ((l >> 4) << 2) + r;
            int node = node0 + row;
            float sg = (node < n) ? sig2[node * 2 + head] : 0.f;
            po[row][cg] = fmaxf(acc[r] + sg * bbv + bbs, 0.f);
        }
    }
    __syncthreads();
    int t = threadIdx.x;
    if (t < 128) {
        int curg = -1;
        float mx = 0.f;
        for (int r = 0; r < 16; ++r) {
            int g = pg[r];
            if (g < 0) continue;
            if (g != curg) {
                if (curg >= 0) atomicMax(&pool[(size_t)curg * 128 + t], __float_as_uint(mx));
                curg = g;
                mx = 0.f;
            }
            mx = fmaxf(mx, po[r][t]);
        }
        if (curg >= 0) atomicMax(&pool[(size_t)curg * 128 + t], __float_as_uint(mx));
    }
}

// ---------------- MLP head ----------------
__global__ void head_kernel(const unsigned* __restrict__ pbits,
                            const float* __restrict__ W1, const float* __restrict__ b1,
                            const float* __restrict__ W2, const float* __restrict__ b2,
                            const float* __restrict__ W3, const float* __restrict__ b3,
                            float* __restrict__ out, int G) {
    int g = blockIdx.x;
    int t = threadIdx.x;  // 128 threads
    __shared__ float ps[128], xl[32], y[128];
    ps[t] = __uint_as_float(pbits[g * 128 + t]);
    __syncthreads();
    if (t < 32) {
        float a = b1[t];
        for (int k = 0; k < 128; ++k) a += ps[k] * W1[k * 32 + t];
        a = fmaxf(a, 0.f);
        xl[t] = a;
        out[G * 40 + g * 32 + t] = a;
    }
    __syncthreads();
    {
        float a = b2[t];
        for (int k = 0; k < 32; ++k) a += xl[k] * W2[k * 128 + t];
        y[t] = fmaxf(a, 0.f);
    }
    __syncthreads();
    if (t < 40) {
        float a = b3[t];
        for (int k = 0; k < 128; ++k) a += y[k] * W3[k * 40 + t];  // W3 is (128,40)
        out[g * 40 + t] = a;
    }
}

extern "C" void kernel_launch(void* const* d_in, const int* in_sizes, int n_in,
                              void* d_out, int out_size, void* d_ws, size_t ws_size,
                              hipStream_t stream) {
    const float* x = (const float*)d_in[0];
    const int* eidx = (const int*)d_in[1];
    const int* batch = (const int*)d_in[2];
    const float *Wq1 = (const float*)d_in[3], *bq1 = (const float*)d_in[4];
    const float *Wk1 = (const float*)d_in[5], *bk1 = (const float*)d_in[6];
    const float *Wv1 = (const float*)d_in[7], *bv1 = (const float*)d_in[8];
    const float *Ws1 = (const float*)d_in[9], *bs1 = (const float*)d_in[10];
    const float *Wq2 = (const float*)d_in[11], *bq2 = (const float*)d_in[12];
    const float *Wk2 = (const float*)d_in[13], *bk2 = (const float*)d_in[14];
    const float *Wv2 = (const float*)d_in[15], *bv2 = (const float*)d_in[16];
    const float *Ws2 = (const float*)d_in[17], *bs2 = (const float*)d_in[18];
    const float *W1 = (const float*)d_in[19], *b1 = (const float*)d_in[20];
    const float *W2 = (const float*)d_in[21], *b2 = (const float*)d_in[22];
    const float *W3 = (const float*)d_in[23], *b3 = (const float*)d_in[24];
    (void)bk1; (void)bk2;  // bk terms cancel in softmax (constant per-dst shift)

    const int N = in_sizes[0] / 3;
    const int E = in_sizes[1] / 2;
    const int G = out_size / 72;  // 40 + 32 per graph
    const int* esrc = eidx;
    const int* edst = eidx + E;
    const int NB = (N + 255) / 256;
    const int EB = (E + 255) / 256;
    const int POOLSZ = G * 128;
    const int PB = (POOLSZ + 255) / 256;
    const int RSIZE = (N + 7) / 8;  // dst-range size per XCD partition

    char* w = (char*)d_ws;
    size_t o = 0;
    auto alloc = [&](size_t bytes) {
        void* p = w + o;
        o = (o + bytes + 255) & ~(size_t)255;
        return p;
    };
    float* c1buf = (float*)alloc(24 * 4);
    float* wcat = (float*)alloc(128 * 4);
    ushort* bfragY = (ushort*)alloc(16 * 512 * 2);
    ushort* B192 = (ushort*)alloc(48 * 512 * 2);
    unsigned* h1b = (unsigned*)alloc((size_t)N * 32 * 4);   // N x 64 bf16
    ushort* Ypb = (ushort*)alloc((size_t)N * 128 * 2);      // N x 128 bf16
    unsigned* a01 = (unsigned*)alloc((size_t)N * 64 * 4);   // N x 128 bf16
    float* sig2 = (float*)alloc((size_t)N * 2 * 4);
    int* deg = (int*)alloc((size_t)N * 4);
    int* off = (int*)alloc((size_t)(N + 1) * 4);
    int* cursor = (int*)alloc((size_t)N * 4);
    int* srcs = (int*)alloc((size_t)E * 4);
    unsigned* pool = (unsigned*)alloc((size_t)POOLSZ * 4);
    int* bsum = (int*)alloc(256 * 4);
    (void)ws_size;

    // fused prep (weights -> c1/wcat/bfragY/B192) + zero deg + zero pool
    prep_all<<<45 + NB + PB, 256, 0, stream>>>(Wq1, bq1, Wk1, Wq2, bq2, Wk2, Wv2, Ws2,
                                               c1buf, wcat, bfragY, B192, deg, pool,
                                               N, NB, POOLSZ);

    // CSR by destination (XCD-partitioned atomics/writes; scan_blocks folded in)
    deg_part<<<8 * EB, 256, 0, stream>>>(edst, deg, E, RSIZE);
    scan_reduce<<<NB, 256, 0, stream>>>(deg, bsum, N);
    scan_apply<<<NB, 256, 0, stream>>>(deg, bsum, off, cursor, N, NB, E);
    scatter_part<<<8 * EB, 256, 0, stream>>>(esrc, edst, cursor, srcs, E, RSIZE);

    // layer 1 (fused: scores via x^T M x, PV via (sum p x), V/skip/relu epilogue)
    attn1f<<<(N + 31) / 32, 256, 0, stream>>>(x, c1buf, Wv1, bv1, Ws1, bs1, off, srcs,
                                              h1b, N);

    // layer 2
    lin2Y<<<(N + 15) / 16, 256, 0, stream>>>((const ushort*)h1b, bfragY, wcat, Ypb, N);
    attn2_kernel<<<(N + 3) / 4, 256, 0, stream>>>(Ypb, h1b, off, srcs, a01,
                                                  (float2*)sig2, N);
    epi2<<<(N + 15) / 16, 256, 0, stream>>>((const ushort*)a01, (const ushort*)h1b, B192,
                                            bv2, bs2, sig2, batch, pool, N);

    // head
    head_kernel<<<G, 128, 0, stream>>>(pool, W1, b1, W2, b2, W3, b3, (float*)d_out, G);
}

// Round 21
// 177.094 us; speedup vs baseline: 1.4560x; 1.0229x over previous
//
#include <hip/hip_runtime.h>
#include <hip/hip_bf16.h>

typedef short s16x8 __attribute__((ext_vector_type(8)));   // 8 bf16 (4 VGPRs)
typedef float f32x4 __attribute__((ext_vector_type(4)));

#define LOG2E 1.4426950408889634f

__device__ __forceinline__ float bfl(unsigned w) { return __uint_as_float(w << 16); }
__device__ __forceinline__ float bfh(unsigned w) { return __uint_as_float(w & 0xffff0000u); }
__device__ __forceinline__ unsigned f2bf(float f) {
    unsigned u = __float_as_uint(f);
    return (u + 0x7fffu + ((u >> 16) & 1u)) >> 16;  // RNE, finite data
}

// ---------------- CSR build (XCD-partitioned by dst range) ----------------
__global__ void deg_part(const int* __restrict__ dst, int* __restrict__ deg,
                         int E, int rsize) {
    int r = blockIdx.x & 7;
    int e = (blockIdx.x >> 3) * blockDim.x + threadIdx.x;
    if (e < E) {
        int d = dst[e];
        if (d / rsize == r) atomicAdd(&deg[d], 1);
    }
}

__global__ void scan_reduce(const int* __restrict__ deg, int* __restrict__ bsum, int n) {
    __shared__ int sh[256];
    int t = threadIdx.x;
    int i = blockIdx.x * 256 + t;
    sh[t] = (i < n) ? deg[i] : 0;
    __syncthreads();
    for (int s = 128; s > 0; s >>= 1) {
        if (t < s) sh[t] += sh[t + s];
        __syncthreads();
    }
    if (t == 0) bsum[blockIdx.x] = sh[0];
}

// scan_apply computes its own block offset (tree-reduce over bsum[k<b]);
// off[n] = E (total degree).
__global__ void scan_apply(const int* __restrict__ deg, const int* __restrict__ bsum,
                           int* __restrict__ off, int* __restrict__ cursor,
                           int n, int nb, int Etot) {
    __shared__ int sh[256], sb[256];
    int t = threadIdx.x;
    int b = blockIdx.x;
    sb[t] = (t < nb && t < b) ? bsum[t] : 0;
    int i = b * 256 + t;
    int v = (i < n) ? deg[i] : 0;
    sh[t] = v;
    __syncthreads();
    for (int s = 128; s > 0; s >>= 1) {
        if (t < s) sb[t] += sb[t + s];
        __syncthreads();
    }
    int boffb = sb[0];
    __syncthreads();
    for (int d = 1; d < 256; d <<= 1) {
        int x = (t >= d) ? sh[t - d] : 0;
        __syncthreads();
        sh[t] += x;
        __syncthreads();
    }
    int ex = sh[t] - v + boffb;
    if (i < n) {
        off[i] = ex;
        cursor[i] = ex;
    }
    if (b == 0 && t == 0) off[n] = Etot;
}

__global__ void scatter_part(const int* __restrict__ src, const int* __restrict__ dst,
                             int* __restrict__ cursor, int* __restrict__ srcs,
                             int E, int rsize) {
    int r = blockIdx.x & 7;
    int e = (blockIdx.x >> 3) * blockDim.x + threadIdx.x;
    if (e < E) {
        int d = dst[e];
        if (d / rsize == r) {
            int p = atomicAdd(&cursor[d], 1);
            srcs[p] = src[e];
        }
    }
}

// ---------------- prep_all: fused weight preprocessing + buffer zeroing ----------
__global__ void prep_all(const float* __restrict__ Wq1, const float* __restrict__ bq1,
                         const float* __restrict__ Wk1,
                         const float* __restrict__ Wq2, const float* __restrict__ bq2,
                         const float* __restrict__ Wk2,
                         const float* __restrict__ Wv2, const float* __restrict__ Ws2,
                         float* __restrict__ c1, float* __restrict__ wcat,
                         ushort* __restrict__ bfragY, ushort* __restrict__ B192,
                         int* __restrict__ deg, unsigned* __restrict__ pool,
                         int n, int nbdeg, int poolsz) {
    int b = blockIdx.x, t = threadIdx.x;
    if (b == 0) {
        if (t < 18) {
            int h = t / 9, rr = t % 9, r = rr / 3, rp = rr % 3;
            float s = 0.f;
            for (int d = 0; d < 32; ++d)
                s += Wq1[r * 64 + h * 32 + d] * Wk1[rp * 64 + h * 32 + d];
            c1[t] = s;
        } else if (t < 24) {
            int u = t - 18, h = u / 3, rp = u % 3;
            float s = 0.f;
            for (int d = 0; d < 32; ++d)
                s += bq1[h * 32 + d] * Wk1[rp * 64 + h * 32 + d];
            c1[t] = s;
        } else if (t >= 64 && t < 192) {
            int cc = t - 64, h = cc >> 6, kp = cc & 63;
            float s = 0.f;
            for (int d = 0; d < 64; ++d)
                s += bq2[h * 64 + d] * Wk2[kp * 128 + h * 64 + d];
            wcat[cc] = s;
        }
    } else if (b < 33) {
        int idx = (b - 1) * 256 + t;  // 0..8191 = Mcat element (k, cc)
        int k = idx >> 7, cc = idx & 127, h = cc >> 6, kp = cc & 63;
        float s = 0.f;
        for (int d = 0; d < 64; ++d)
            s += Wq2[k * 128 + h * 64 + d] * Wk2[kp * 128 + h * 64 + d];
        int frag = ((cc >> 4) << 1) | (k >> 5);
        int l = (cc & 15) | (((k >> 3) & 3) << 4);
        bfragY[(size_t)frag * 512 + l * 8 + (k & 7)] = (ushort)f2bf(s);
    } else if (b < 45) {
        int tt = (b - 33) * 256 + t;  // 0..3071 (48 frags x 64 lanes)
        int frag = tt >> 6, l = tt & 63;
        int ct = frag / 6, ks = frag % 6;
        int c = ct * 16 + (l & 15);
        int kbase = ks * 32 + ((l >> 4) << 3);
#pragma unroll
        for (int e = 0; e < 8; ++e) {
            int k = kbase + e;
            float v;
            if (k < 64) v = (c < 64) ? Wv2[k * 128 + c] : 0.f;
            else if (k < 128) v = (c >= 64) ? Wv2[(k - 64) * 128 + c] : 0.f;
            else v = Ws2[(k - 128) * 128 + c];
            B192[(size_t)frag * 512 + l * 8 + e] = (ushort)f2bf(v);
        }
    } else if (b < 45 + nbdeg) {
        int i = (b - 45) * 256 + t;
        if (i < n) deg[i] = 0;
    } else {
        int i = (b - 45 - nbdeg) * 256 + t;
        if (i < poolsz) pool[i] = 0;
    }
}

// ---------------- attn1f: layer-1 attention, head-split lanes --------------------
// 16 lanes/node (4 nodes/wave): half hh=(lane&15)>>3 owns head hh; es=lane&7 is
// the edge slot (every-8th edge; both halves read the same edges — same addrs).
// Per edge: 3-FMA dot + 1 exp + 4 accums. Merge = 3 rounds x 4 values within the
// 8-lane half. Epilogue: lane owns 4 channels of ITS head: c = hh*32 + 4*es.
__global__ __launch_bounds__(256) void attn1f(
        const float* __restrict__ x, const float* __restrict__ c1,
        const float* __restrict__ Wv, const float* __restrict__ bv,
        const float* __restrict__ Ws, const float* __restrict__ bs,
        const int* __restrict__ off, const int* __restrict__ srcs,
        unsigned* __restrict__ h1b, int n) {
    int lane = threadIdx.x & 63;
    int g = lane >> 4;
    int sl16 = lane & 15;
    int hh = sl16 >> 3, es = sl16 & 7;
    int i = (blockIdx.x * (blockDim.x >> 6) + (threadIdx.x >> 6)) * 4 + g;
    bool act = i < n;
    int ic = act ? i : 0;
    float x0 = x[ic * 3], x1 = x[ic * 3 + 1], x2 = x[ic * 3 + 2];
    float y[3];
#pragma unroll
    for (int rp = 0; rp < 3; ++rp)
        y[rp] = x0 * c1[hh * 9 + rp] + x1 * c1[hh * 9 + 3 + rp] +
                x2 * c1[hh * 9 + 6 + rp] + c1[18 + hh * 3 + rp];
    const float SC = 0.17677669529663688f * LOG2E;  // 1/sqrt(32) * log2(e)
    int e0 = act ? off[ic] : 0, e1 = act ? off[ic + 1] : 0;
    float d = 0.f, ax = 0.f, ay = 0.f, az = 0.f;
    for (int e = e0 + es; e < e1; e += 8) {
        int j = srcs[e];
        float xj0 = x[j * 3], xj1 = x[j * 3 + 1], xj2 = x[j * 3 + 2];
        float p = exp2f((y[0] * xj0 + y[1] * xj1 + y[2] * xj2) * SC);
        d += p; ax += p * xj0; ay += p * xj1; az += p * xj2;
    }
    // merge the 8 edge slots (within the half; masks are es bits)
#pragma unroll
    for (int mask = 1; mask <= 4; mask <<= 1) {
        d += __shfl_xor(d, mask);
        ax += __shfl_xor(ax, mask);
        ay += __shfl_xor(ay, mask);
        az += __shfl_xor(az, mask);
    }
    if (!act) return;
    float inv = 1.f / fmaxf(d, 1e-16f);
    float sg = d > 0.f ? 1.f : 0.f;
    float Ax = ax * inv, Ay = ay * inv, Az = az * inv;
    unsigned pk[2];
#pragma unroll
    for (int u = 0; u < 2; ++u) {
        int c = hh * 32 + 4 * es + 2 * u;
        float2 wv0 = *(const float2*)&Wv[c], wv1 = *(const float2*)&Wv[64 + c],
               wv2 = *(const float2*)&Wv[128 + c];
        float2 ws0 = *(const float2*)&Ws[c], ws1 = *(const float2*)&Ws[64 + c],
               ws2 = *(const float2*)&Ws[128 + c];
        float2 bbv = *(const float2*)&bv[c];
        float2 bbs = *(const float2*)&bs[c];
        float v0 = Ax * wv0.x + Ay * wv1.x + Az * wv2.x + sg * bbv.x +
                   x0 * ws0.x + x1 * ws1.x + x2 * ws2.x + bbs.x;
        float v1 = Ax * wv0.y + Ay * wv1.y + Az * wv2.y + sg * bbv.y +
                   x0 * ws0.y + x1 * ws1.y + x2 * ws2.y + bbs.y;
        pk[u] = f2bf(fmaxf(v0, 0.f)) | (f2bf(fmaxf(v1, 0.f)) << 16);
    }
    uint2 pw = {pk[0], pk[1]};
    *(uint2*)&h1b[(size_t)i * 32 + hh * 16 + 2 * es] = pw;
}

// ---------------- lin2Y: Y' = h1 @ Mcat + wcat (MFMA, N x 128 bf16) --------------
__global__ __launch_bounds__(256) void lin2Y(const ushort* __restrict__ h1b,
                                             const ushort* __restrict__ bfragY,
                                             const float* __restrict__ wcat,
                                             ushort* __restrict__ Ypb, int n) {
    int node0 = blockIdx.x * 16;
    int w = threadIdx.x >> 6, l = threadIdx.x & 63;
    int arow = node0 + (l & 15);
    if (arow >= n) arow = n - 1;
    s16x8 a0 = *(const s16x8*)&h1b[(size_t)arow * 64 + ((l >> 4) << 3)];
    s16x8 a1 = *(const s16x8*)&h1b[(size_t)arow * 64 + 32 + ((l >> 4) << 3)];
    int cl = l & 15;
#pragma unroll
    for (int qq = 0; qq < 2; ++qq) {
        int ct = w * 2 + qq;
        s16x8 b0 = *(const s16x8*)&bfragY[(size_t)(ct * 2 + 0) * 512 + l * 8];
        s16x8 b1 = *(const s16x8*)&bfragY[(size_t)(ct * 2 + 1) * 512 + l * 8];
        f32x4 acc = {0.f, 0.f, 0.f, 0.f};
        acc = __builtin_amdgcn_mfma_f32_16x16x32_bf16(a0, b0, acc, 0, 0, 0);
        acc = __builtin_amdgcn_mfma_f32_16x16x32_bf16(a1, b1, acc, 0, 0, 0);
        int cg = ct * 16 + cl;
        float bb = wcat[cg];
#pragma unroll
        for (int r = 0; r < 4; ++r) {
            int node = node0 + ((l >> 4) << 2) + r;
            if (node < n) Ypb[(size_t)node * 128 + cg] = (ushort)f2bf(acc[r] + bb);
        }
    }
}

// ---------------- attn2: no-max softmax, head-split lanes -------------------------
// 4 groups (qd=lane>>4) x 16 lanes; within a group, half hh=(lane&15)>>3 owns head
// hh, cb=lane&7 owns h-channels 8cb..8cb+7 (uint4). Both halves load the same h.
// Per edge: 8-FMA dot (own head) + 3 shuffles + 1 exp + 8 accums. Merge = 2 rounds
// x 9 values across groups.
__global__ __launch_bounds__(256) void attn2_kernel(
        const ushort* __restrict__ Ypb, const unsigned* __restrict__ h1u,
        const int* __restrict__ off, const int* __restrict__ srcs,
        unsigned* __restrict__ a01, float* __restrict__ sig2f, int n) {
    int i = blockIdx.x * (blockDim.x >> 6) + (threadIdx.x >> 6);
    int lane = threadIdx.x & 63;
    if (i >= n) return;
    int qd = lane >> 4;
    int sl16 = lane & 15;
    int hh = sl16 >> 3, cb = sl16 & 7;
    int e0 = off[i], e1 = off[i + 1];
    const float SC = 0.125f * LOG2E;  // 1/sqrt(64) * log2(e)
    uint4 yu = *(const uint4*)&Ypb[(size_t)i * 128 + hh * 64 + 8 * cb];
    float y[8];
    y[0] = bfl(yu.x); y[1] = bfh(yu.x); y[2] = bfl(yu.y); y[3] = bfh(yu.y);
    y[4] = bfl(yu.z); y[5] = bfh(yu.z); y[6] = bfl(yu.w); y[7] = bfh(yu.w);
    float d = 0.f;
    float a[8] = {0.f, 0.f, 0.f, 0.f, 0.f, 0.f, 0.f, 0.f};
    for (int e = e0 + qd; e < e1; e += 4) {
        int j = srcs[e];
        uint4 hb = *(const uint4*)&h1u[(size_t)j * 32 + 4 * cb];
        float h[8];
        h[0] = bfl(hb.x); h[1] = bfh(hb.x); h[2] = bfl(hb.y); h[3] = bfh(hb.y);
        h[4] = bfl(hb.z); h[5] = bfh(hb.z); h[6] = bfl(hb.w); h[7] = bfh(hb.w);
        float t = y[0] * h[0] + y[1] * h[1] + y[2] * h[2] + y[3] * h[3] +
                  y[4] * h[4] + y[5] * h[5] + y[6] * h[6] + y[7] * h[7];
        t += __shfl_xor(t, 1);
        t += __shfl_xor(t, 2);
        t += __shfl_xor(t, 4);
        float p = exp2f(t * SC);
        d += p;
#pragma unroll
        for (int k = 0; k < 8; ++k) a[k] += p * h[k];
    }
    // merge the 4 groups (plain sums; 9 live values)
#pragma unroll
    for (int mask = 16; mask <= 32; mask <<= 1) {
        d += __shfl_xor(d, mask);
#pragma unroll
        for (int k = 0; k < 8; ++k) a[k] += __shfl_xor(a[k], mask);
    }
    if (qd == 0) {
        float inv = 1.f / fmaxf(d, 1e-16f);
        uint4 pk;
        pk.x = f2bf(a[0] * inv) | (f2bf(a[1] * inv) << 16);
        pk.y = f2bf(a[2] * inv) | (f2bf(a[3] * inv) << 16);
        pk.z = f2bf(a[4] * inv) | (f2bf(a[5] * inv) << 16);
        pk.w = f2bf(a[6] * inv) | (f2bf(a[7] * inv) << 16);
        *(uint4*)&a01[(size_t)i * 64 + hh * 32 + 4 * cb] = pk;
        if (cb == 0) sig2f[i * 2 + hh] = d > 0.f ? 1.f : 0.f;
    }
}

// ---------------- epi2: out = relu([a0|a1|h1]@B192 + sigma*bv + bs) + LDS pool ----
__global__ __launch_bounds__(256) void epi2(
        const ushort* __restrict__ a01, const ushort* __restrict__ h1b,
        const ushort* __restrict__ B192, const float* __restrict__ bv,
        const float* __restrict__ bs, const float* __restrict__ sig2,
        const int* __restrict__ batch, unsigned* __restrict__ pool, int n) {
    __shared__ float po[16][128];
    __shared__ int pg[16];
    int node0 = blockIdx.x * 16;
    int w = threadIdx.x >> 6, l = threadIdx.x & 63;
    int arow = node0 + (l & 15);
    int arc = (arow < n) ? arow : (n - 1);
    int koff = (l >> 4) << 3;
    s16x8 af[6];
    af[0] = *(const s16x8*)&a01[(size_t)arc * 128 + 0 + koff];
    af[1] = *(const s16x8*)&a01[(size_t)arc * 128 + 32 + koff];
    af[2] = *(const s16x8*)&a01[(size_t)arc * 128 + 64 + koff];
    af[3] = *(const s16x8*)&a01[(size_t)arc * 128 + 96 + koff];
    af[4] = *(const s16x8*)&h1b[(size_t)arc * 64 + 0 + koff];
    af[5] = *(const s16x8*)&h1b[(size_t)arc * 64 + 32 + koff];
    if (threadIdx.x < 16)
        pg[threadIdx.x] = (node0 + threadIdx.x < n) ? batch[node0 + threadIdx.x] : -1;
    int cl = l & 15;
#pragma unroll
    for (int qq = 0; qq < 2; ++qq) {
        int ct = w * 2 + qq;
        f32x4 acc = {0.f, 0.f, 0.f, 0.f};
#pragma unroll
        for (int ks = 0; ks < 6; ++ks) {
            s16x8 b = *(const s16x8*)&B192[(size_t)(ct * 6 + ks) * 512 + l * 8];
            acc = __builtin_amdgcn_mfma_f32_16x16x32_bf16(af[ks], b, acc, 0, 0, 0);
        }
        int cg = ct * 16 + cl;
        int head = cg >> 6;
        float bbs = bs[cg], bbv = bv[cg];
#pragma unroll
        for (int r = 0; r < 4; ++r) {
            int row = ((l >> 4) << 2) + r;
            int node = node0 + row;
            float sg = (node < n) ? sig2[node * 2 + head] : 0.f;
            po[row][cg] = fmaxf(acc[r] + sg * bbv + bbs, 0.f);
        }
    }
    __syncthreads();
    int t = threadIdx.x;
    if (t < 128) {
        int curg = -1;
        float mx = 0.f;
        for (int r = 0; r < 16; ++r) {
            int g = pg[r];
            if (g < 0) continue;
            if (g != curg) {
                if (curg >= 0) atomicMax(&pool[(size_t)curg * 128 + t], __float_as_uint(mx));
                curg = g;
                mx = 0.f;
            }
            mx = fmaxf(mx, po[r][t]);
        }
        if (curg >= 0) atomicMax(&pool[(size_t)curg * 128 + t], __float_as_uint(mx));
    }
}

// ---------------- MLP head ----------------
__global__ void head_kernel(const unsigned* __restrict__ pbits,
                            const float* __restrict__ W1, const float* __restrict__ b1,
                            const float* __restrict__ W2, const float* __restrict__ b2,
                            const float* __restrict__ W3, const float* __restrict__ b3,
                            float* __restrict__ out, int G) {
    int g = blockIdx.x;
    int t = threadIdx.x;  // 128 threads
    __shared__ float ps[128], xl[32], y[128];
    ps[t] = __uint_as_float(pbits[g * 128 + t]);
    __syncthreads();
    if (t < 32) {
        float a = b1[t];
        for (int k = 0; k < 128; ++k) a += ps[k] * W1[k * 32 + t];
        a = fmaxf(a, 0.f);
        xl[t] = a;
        out[G * 40 + g * 32 + t] = a;
    }
    __syncthreads();
    {
        float a = b2[t];
        for (int k = 0; k < 32; ++k) a += xl[k] * W2[k * 128 + t];
        y[t] = fmaxf(a, 0.f);
    }
    __syncthreads();
    if (t < 40) {
        float a = b3[t];
        for (int k = 0; k < 128; ++k) a += y[k] * W3[k * 40 + t];  // W3 is (128,40)
        out[g * 40 + t] = a;
    }
}

extern "C" void kernel_launch(void* const* d_in, const int* in_sizes, int n_in,
                              void* d_out, int out_size, void* d_ws, size_t ws_size,
                              hipStream_t stream) {
    const float* x = (const float*)d_in[0];
    const int* eidx = (const int*)d_in[1];
    const int* batch = (const int*)d_in[2];
    const float *Wq1 = (const float*)d_in[3], *bq1 = (const float*)d_in[4];
    const float *Wk1 = (const float*)d_in[5], *bk1 = (const float*)d_in[6];
    const float *Wv1 = (const float*)d_in[7], *bv1 = (const float*)d_in[8];
    const float *Ws1 = (const float*)d_in[9], *bs1 = (const float*)d_in[10];
    const float *Wq2 = (const float*)d_in[11], *bq2 = (const float*)d_in[12];
    const float *Wk2 = (const float*)d_in[13], *bk2 = (const float*)d_in[14];
    const float *Wv2 = (const float*)d_in[15], *bv2 = (const float*)d_in[16];
    const float *Ws2 = (const float*)d_in[17], *bs2 = (const float*)d_in[18];
    const float *W1 = (const float*)d_in[19], *b1 = (const float*)d_in[20];
    const float *W2 = (const float*)d_in[21], *b2 = (const float*)d_in[22];
    const float *W3 = (const float*)d_in[23], *b3 = (const float*)d_in[24];
    (void)bk1; (void)bk2;  // bk terms cancel in softmax (constant per-dst shift)

    const int N = in_sizes[0] / 3;
    const int E = in_sizes[1] / 2;
    const int G = out_size / 72;  // 40 + 32 per graph
    const int* esrc = eidx;
    const int* edst = eidx + E;
    const int NB = (N + 255) / 256;
    const int EB = (E + 255) / 256;
    const int POOLSZ = G * 128;
    const int PB = (POOLSZ + 255) / 256;
    const int RSIZE = (N + 7) / 8;  // dst-range size per XCD partition

    char* w = (char*)d_ws;
    size_t o = 0;
    auto alloc = [&](size_t bytes) {
        void* p = w + o;
        o = (o + bytes + 255) & ~(size_t)255;
        return p;
    };
    float* c1buf = (float*)alloc(24 * 4);
    float* wcat = (float*)alloc(128 * 4);
    ushort* bfragY = (ushort*)alloc(16 * 512 * 2);
    ushort* B192 = (ushort*)alloc(48 * 512 * 2);
    unsigned* h1b = (unsigned*)alloc((size_t)N * 32 * 4);   // N x 64 bf16
    ushort* Ypb = (ushort*)alloc((size_t)N * 128 * 2);      // N x 128 bf16
    unsigned* a01 = (unsigned*)alloc((size_t)N * 64 * 4);   // N x 128 bf16
    float* sig2 = (float*)alloc((size_t)N * 2 * 4);
    int* deg = (int*)alloc((size_t)N * 4);
    int* off = (int*)alloc((size_t)(N + 1) * 4);
    int* cursor = (int*)alloc((size_t)N * 4);
    int* srcs = (int*)alloc((size_t)E * 4);
    unsigned* pool = (unsigned*)alloc((size_t)POOLSZ * 4);
    int* bsum = (int*)alloc(256 * 4);
    (void)ws_size;

    // fused prep (weights -> c1/wcat/bfragY/B192) + zero deg + zero pool
    prep_all<<<45 + NB + PB, 256, 0, stream>>>(Wq1, bq1, Wk1, Wq2, bq2, Wk2, Wv2, Ws2,
                                               c1buf, wcat, bfragY, B192, deg, pool,
                                               N, NB, POOLSZ);

    // CSR by destination (XCD-partitioned atomics/writes)
    deg_part<<<8 * EB, 256, 0, stream>>>(edst, deg, E, RSIZE);
    scan_reduce<<<NB, 256, 0, stream>>>(deg, bsum, N);
    scan_apply<<<NB, 256, 0, stream>>>(deg, bsum, off, cursor, N, NB, E);
    scatter_part<<<8 * EB, 256, 0, stream>>>(esrc, edst, cursor, srcs, E, RSIZE);

    // layer 1 (fused, head-split lanes)
    attn1f<<<(N + 15) / 16, 256, 0, stream>>>(x, c1buf, Wv1, bv1, Ws1, bs1, off, srcs,
                                              h1b, N);

    // layer 2
    lin2Y<<<(N + 15) / 16, 256, 0, stream>>>((const ushort*)h1b, bfragY, wcat, Ypb, N);
    attn2_kernel<<<(N + 3) / 4, 256, 0, stream>>>(Ypb, h1b, off, srcs, a01, sig2, N);
    epi2<<<(N + 15) / 16, 256, 0, stream>>>((const ushort*)a01, (const ushort*)h1b, B192,
                                            bv2, bs2, sig2, batch, pool, N);

    // head
    head_kernel<<<G, 128, 0, stream>>>(pool, W1, b1, W2, b2, W3, b3, (float*)d_out, G);
}

// Round 22
// 169.056 us; speedup vs baseline: 1.5252x; 1.0475x over previous
//
#include <hip/hip_runtime.h>
#include <hip/hip_bf16.h>

typedef short s16x8 __attribute__((ext_vector_type(8)));   // 8 bf16 (4 VGPRs)
typedef float f32x4 __attribute__((ext_vector_type(4)));

#define LOG2E 1.4426950408889634f

__device__ __forceinline__ float bfl(unsigned w) { return __uint_as_float(w << 16); }
__device__ __forceinline__ float bfh(unsigned w) { return __uint_as_float(w & 0xffff0000u); }
__device__ __forceinline__ unsigned f2bf(float f) {
    unsigned u = __float_as_uint(f);
    return (u + 0x7fffu + ((u >> 16) & 1u)) >> 16;  // RNE, finite data
}

// ---------------- CSR build (XCD-partitioned by dst range) ----------------
__global__ void deg_part(const int* __restrict__ dst, int* __restrict__ deg,
                         int E, int rsize) {
    int r = blockIdx.x & 7;
    int e = (blockIdx.x >> 3) * blockDim.x + threadIdx.x;
    if (e < E) {
        int d = dst[e];
        if (d / rsize == r) atomicAdd(&deg[d], 1);
    }
}

__global__ void scan_reduce(const int* __restrict__ deg, int* __restrict__ bsum, int n) {
    __shared__ int sh[256];
    int t = threadIdx.x;
    int i = blockIdx.x * 256 + t;
    sh[t] = (i < n) ? deg[i] : 0;
    __syncthreads();
    for (int s = 128; s > 0; s >>= 1) {
        if (t < s) sh[t] += sh[t + s];
        __syncthreads();
    }
    if (t == 0) bsum[blockIdx.x] = sh[0];
}

// scan_apply computes its own block offset (tree-reduce over bsum[k<b]);
// off[n] = E (total degree).
__global__ void scan_apply(const int* __restrict__ deg, const int* __restrict__ bsum,
                           int* __restrict__ off, int* __restrict__ cursor,
                           int n, int nb, int Etot) {
    __shared__ int sh[256], sb[256];
    int t = threadIdx.x;
    int b = blockIdx.x;
    sb[t] = (t < nb && t < b) ? bsum[t] : 0;
    int i = b * 256 + t;
    int v = (i < n) ? deg[i] : 0;
    sh[t] = v;
    __syncthreads();
    for (int s = 128; s > 0; s >>= 1) {
        if (t < s) sb[t] += sb[t + s];
        __syncthreads();
    }
    int boffb = sb[0];
    __syncthreads();
    for (int d = 1; d < 256; d <<= 1) {
        int x = (t >= d) ? sh[t - d] : 0;
        __syncthreads();
        sh[t] += x;
        __syncthreads();
    }
    int ex = sh[t] - v + boffb;
    if (i < n) {
        off[i] = ex;
        cursor[i] = ex;
    }
    if (b == 0 && t == 0) off[n] = Etot;
}

__global__ void scatter_part(const int* __restrict__ src, const int* __restrict__ dst,
                             int* __restrict__ cursor, int* __restrict__ srcs,
                             int E, int rsize) {
    int r = blockIdx.x & 7;
    int e = (blockIdx.x >> 3) * blockDim.x + threadIdx.x;
    if (e < E) {
        int d = dst[e];
        if (d / rsize == r) {
            int p = atomicAdd(&cursor[d], 1);
            srcs[p] = src[e];
        }
    }
}

// ---------------- prep_all: fused weight preprocessing + buffer zeroing ----------
__global__ void prep_all(const float* __restrict__ Wq1, const float* __restrict__ bq1,
                         const float* __restrict__ Wk1,
                         const float* __restrict__ Wq2, const float* __restrict__ bq2,
                         const float* __restrict__ Wk2,
                         const float* __restrict__ Wv2, const float* __restrict__ Ws2,
                         float* __restrict__ c1, float* __restrict__ wcat,
                         ushort* __restrict__ bfragY, ushort* __restrict__ B192,
                         int* __restrict__ deg, unsigned* __restrict__ pool,
                         int n, int nbdeg, int poolsz) {
    int b = blockIdx.x, t = threadIdx.x;
    if (b == 0) {
        if (t < 18) {
            int h = t / 9, rr = t % 9, r = rr / 3, rp = rr % 3;
            float s = 0.f;
            for (int d = 0; d < 32; ++d)
                s += Wq1[r * 64 + h * 32 + d] * Wk1[rp * 64 + h * 32 + d];
            c1[t] = s;
        } else if (t < 24) {
            int u = t - 18, h = u / 3, rp = u % 3;
            float s = 0.f;
            for (int d = 0; d < 32; ++d)
                s += bq1[h * 32 + d] * Wk1[rp * 64 + h * 32 + d];
            c1[t] = s;
        } else if (t >= 64 && t < 192) {
            int cc = t - 64, h = cc >> 6, kp = cc & 63;
            float s = 0.f;
            for (int d = 0; d < 64; ++d)
                s += bq2[h * 64 + d] * Wk2[kp * 128 + h * 64 + d];
            wcat[cc] = s;
        }
    } else if (b < 33) {
        int idx = (b - 1) * 256 + t;  // 0..8191 = Mcat element (k, cc)
        int k = idx >> 7, cc = idx & 127, h = cc >> 6, kp = cc & 63;
        float s = 0.f;
        for (int d = 0; d < 64; ++d)
            s += Wq2[k * 128 + h * 64 + d] * Wk2[kp * 128 + h * 64 + d];
        int frag = ((cc >> 4) << 1) | (k >> 5);
        int l = (cc & 15) | (((k >> 3) & 3) << 4);
        bfragY[(size_t)frag * 512 + l * 8 + (k & 7)] = (ushort)f2bf(s);
    } else if (b < 45) {
        int tt = (b - 33) * 256 + t;  // 0..3071 (48 frags x 64 lanes)
        int frag = tt >> 6, l = tt & 63;
        int ct = frag / 6, ks = frag % 6;
        int c = ct * 16 + (l & 15);
        int kbase = ks * 32 + ((l >> 4) << 3);
#pragma unroll
        for (int e = 0; e < 8; ++e) {
            int k = kbase + e;
            float v;
            if (k < 64) v = (c < 64) ? Wv2[k * 128 + c] : 0.f;
            else if (k < 128) v = (c >= 64) ? Wv2[(k - 64) * 128 + c] : 0.f;
            else v = Ws2[(k - 128) * 128 + c];
            B192[(size_t)frag * 512 + l * 8 + e] = (ushort)f2bf(v);
        }
    } else if (b < 45 + nbdeg) {
        int i = (b - 45) * 256 + t;
        if (i < n) deg[i] = 0;
    } else {
        int i = (b - 45 - nbdeg) * 256 + t;
        if (i < poolsz) pool[i] = 0;
    }
}

// ---------------- attn1f: layer-1 attention, head-split lanes, paired edges ------
// 16 lanes/node (4 nodes/wave): half hh owns head hh; es=lane&7 = edge slot
// (every-8th edge). Edges processed TWO per iteration with hoisted loads
// (doubles memory-level parallelism; halves the dependent srcs->x chain).
__global__ __launch_bounds__(256) void attn1f(
        const float* __restrict__ x, const float* __restrict__ c1,
        const float* __restrict__ Wv, const float* __restrict__ bv,
        const float* __restrict__ Ws, const float* __restrict__ bs,
        const int* __restrict__ off, const int* __restrict__ srcs,
        unsigned* __restrict__ h1b, int n) {
    int lane = threadIdx.x & 63;
    int g = lane >> 4;
    int sl16 = lane & 15;
    int hh = sl16 >> 3, es = sl16 & 7;
    int i = (blockIdx.x * (blockDim.x >> 6) + (threadIdx.x >> 6)) * 4 + g;
    bool act = i < n;
    int ic = act ? i : 0;
    float x0 = x[ic * 3], x1 = x[ic * 3 + 1], x2 = x[ic * 3 + 2];
    float y[3];
#pragma unroll
    for (int rp = 0; rp < 3; ++rp)
        y[rp] = x0 * c1[hh * 9 + rp] + x1 * c1[hh * 9 + 3 + rp] +
                x2 * c1[hh * 9 + 6 + rp] + c1[18 + hh * 3 + rp];
    const float SC = 0.17677669529663688f * LOG2E;  // 1/sqrt(32) * log2(e)
    int e0 = act ? off[ic] : 0, e1 = act ? off[ic + 1] : 0;
    float d = 0.f, ax = 0.f, ay = 0.f, az = 0.f;
    int e = e0 + es;
    for (; e + 8 < e1; e += 16) {
        int j0 = srcs[e], j1 = srcs[e + 8];
        float xa0 = x[j0 * 3], xa1 = x[j0 * 3 + 1], xa2 = x[j0 * 3 + 2];
        float xb0 = x[j1 * 3], xb1 = x[j1 * 3 + 1], xb2 = x[j1 * 3 + 2];
        float p0 = exp2f((y[0] * xa0 + y[1] * xa1 + y[2] * xa2) * SC);
        float p1 = exp2f((y[0] * xb0 + y[1] * xb1 + y[2] * xb2) * SC);
        d += p0 + p1;
        ax += p0 * xa0 + p1 * xb0;
        ay += p0 * xa1 + p1 * xb1;
        az += p0 * xa2 + p1 * xb2;
    }
    if (e < e1) {
        int j = srcs[e];
        float xj0 = x[j * 3], xj1 = x[j * 3 + 1], xj2 = x[j * 3 + 2];
        float p = exp2f((y[0] * xj0 + y[1] * xj1 + y[2] * xj2) * SC);
        d += p; ax += p * xj0; ay += p * xj1; az += p * xj2;
    }
    // merge the 8 edge slots (within the half; masks are es bits)
#pragma unroll
    for (int mask = 1; mask <= 4; mask <<= 1) {
        d += __shfl_xor(d, mask);
        ax += __shfl_xor(ax, mask);
        ay += __shfl_xor(ay, mask);
        az += __shfl_xor(az, mask);
    }
    if (!act) return;
    float inv = 1.f / fmaxf(d, 1e-16f);
    float sg = d > 0.f ? 1.f : 0.f;
    float Ax = ax * inv, Ay = ay * inv, Az = az * inv;
    unsigned pk[2];
#pragma unroll
    for (int u = 0; u < 2; ++u) {
        int c = hh * 32 + 4 * es + 2 * u;
        float2 wv0 = *(const float2*)&Wv[c], wv1 = *(const float2*)&Wv[64 + c],
               wv2 = *(const float2*)&Wv[128 + c];
        float2 ws0 = *(const float2*)&Ws[c], ws1 = *(const float2*)&Ws[64 + c],
               ws2 = *(const float2*)&Ws[128 + c];
        float2 bbv = *(const float2*)&bv[c];
        float2 bbs = *(const float2*)&bs[c];
        float v0 = Ax * wv0.x + Ay * wv1.x + Az * wv2.x + sg * bbv.x +
                   x0 * ws0.x + x1 * ws1.x + x2 * ws2.x + bbs.x;
        float v1 = Ax * wv0.y + Ay * wv1.y + Az * wv2.y + sg * bbv.y +
                   x0 * ws0.y + x1 * ws1.y + x2 * ws2.y + bbs.y;
        pk[u] = f2bf(fmaxf(v0, 0.f)) | (f2bf(fmaxf(v1, 0.f)) << 16);
    }
    uint2 pw = {pk[0], pk[1]};
    *(uint2*)&h1b[(size_t)i * 32 + hh * 16 + 2 * es] = pw;
}

// ---------------- lin2Y: Y' = h1 @ Mcat + wcat (MFMA, N x 128 bf16) --------------
__global__ __launch_bounds__(256) void lin2Y(const ushort* __restrict__ h1b,
                                             const ushort* __restrict__ bfragY,
                                             const float* __restrict__ wcat,
                                             ushort* __restrict__ Ypb, int n) {
    int node0 = blockIdx.x * 16;
    int w = threadIdx.x >> 6, l = threadIdx.x & 63;
    int arow = node0 + (l & 15);
    if (arow >= n) arow = n - 1;
    s16x8 a0 = *(const s16x8*)&h1b[(size_t)arow * 64 + ((l >> 4) << 3)];
    s16x8 a1 = *(const s16x8*)&h1b[(size_t)arow * 64 + 32 + ((l >> 4) << 3)];
    int cl = l & 15;
#pragma unroll
    for (int qq = 0; qq < 2; ++qq) {
        int ct = w * 2 + qq;
        s16x8 b0 = *(const s16x8*)&bfragY[(size_t)(ct * 2 + 0) * 512 + l * 8];
        s16x8 b1 = *(const s16x8*)&bfragY[(size_t)(ct * 2 + 1) * 512 + l * 8];
        f32x4 acc = {0.f, 0.f, 0.f, 0.f};
        acc = __builtin_amdgcn_mfma_f32_16x16x32_bf16(a0, b0, acc, 0, 0, 0);
        acc = __builtin_amdgcn_mfma_f32_16x16x32_bf16(a1, b1, acc, 0, 0, 0);
        int cg = ct * 16 + cl;
        float bb = wcat[cg];
#pragma unroll
        for (int r = 0; r < 4; ++r) {
            int node = node0 + ((l >> 4) << 2) + r;
            if (node < n) Ypb[(size_t)node * 128 + cg] = (ushort)f2bf(acc[r] + bb);
        }
    }
}

// ---------------- attn2: no-max softmax, head-split lanes, paired edges -----------
// 4 groups (qd) x 16 lanes; half hh owns head hh, cb=lane&7 owns 8 channels.
// Two edges per iteration: j0/j1 loads hoisted, both h-gathers independent,
// two interleaved shuffle-reduce chains. Merge = 2 rounds x 9 values.
__global__ __launch_bounds__(256) void attn2_kernel(
        const ushort* __restrict__ Ypb, const unsigned* __restrict__ h1u,
        const int* __restrict__ off, const int* __restrict__ srcs,
        unsigned* __restrict__ a01, float* __restrict__ sig2f, int n) {
    int i = blockIdx.x * (blockDim.x >> 6) + (threadIdx.x >> 6);
    int lane = threadIdx.x & 63;
    if (i >= n) return;
    int qd = lane >> 4;
    int sl16 = lane & 15;
    int hh = sl16 >> 3, cb = sl16 & 7;
    int e0 = off[i], e1 = off[i + 1];
    const float SC = 0.125f * LOG2E;  // 1/sqrt(64) * log2(e)
    uint4 yu = *(const uint4*)&Ypb[(size_t)i * 128 + hh * 64 + 8 * cb];
    float y[8];
    y[0] = bfl(yu.x); y[1] = bfh(yu.x); y[2] = bfl(yu.y); y[3] = bfh(yu.y);
    y[4] = bfl(yu.z); y[5] = bfh(yu.z); y[6] = bfl(yu.w); y[7] = bfh(yu.w);
    float d = 0.f;
    float a[8] = {0.f, 0.f, 0.f, 0.f, 0.f, 0.f, 0.f, 0.f};
    int e = e0 + qd;
    for (; e + 4 < e1; e += 8) {
        int j0 = srcs[e], j1 = srcs[e + 4];
        uint4 hb0 = *(const uint4*)&h1u[(size_t)j0 * 32 + 4 * cb];
        uint4 hb1 = *(const uint4*)&h1u[(size_t)j1 * 32 + 4 * cb];
        float h0[8], h1v[8];
        h0[0] = bfl(hb0.x); h0[1] = bfh(hb0.x); h0[2] = bfl(hb0.y); h0[3] = bfh(hb0.y);
        h0[4] = bfl(hb0.z); h0[5] = bfh(hb0.z); h0[6] = bfl(hb0.w); h0[7] = bfh(hb0.w);
        h1v[0] = bfl(hb1.x); h1v[1] = bfh(hb1.x); h1v[2] = bfl(hb1.y); h1v[3] = bfh(hb1.y);
        h1v[4] = bfl(hb1.z); h1v[5] = bfh(hb1.z); h1v[6] = bfl(hb1.w); h1v[7] = bfh(hb1.w);
        float t0 = y[0] * h0[0] + y[1] * h0[1] + y[2] * h0[2] + y[3] * h0[3] +
                   y[4] * h0[4] + y[5] * h0[5] + y[6] * h0[6] + y[7] * h0[7];
        float t1 = y[0] * h1v[0] + y[1] * h1v[1] + y[2] * h1v[2] + y[3] * h1v[3] +
                   y[4] * h1v[4] + y[5] * h1v[5] + y[6] * h1v[6] + y[7] * h1v[7];
        t0 += __shfl_xor(t0, 1); t1 += __shfl_xor(t1, 1);
        t0 += __shfl_xor(t0, 2); t1 += __shfl_xor(t1, 2);
        t0 += __shfl_xor(t0, 4); t1 += __shfl_xor(t1, 4);
        float p0 = exp2f(t0 * SC);
        float p1 = exp2f(t1 * SC);
        d += p0 + p1;
#pragma unroll
        for (int k = 0; k < 8; ++k) a[k] += p0 * h0[k] + p1 * h1v[k];
    }
    if (e < e1) {
        int j = srcs[e];
        uint4 hb = *(const uint4*)&h1u[(size_t)j * 32 + 4 * cb];
        float h[8];
        h[0] = bfl(hb.x); h[1] = bfh(hb.x); h[2] = bfl(hb.y); h[3] = bfh(hb.y);
        h[4] = bfl(hb.z); h[5] = bfh(hb.z); h[6] = bfl(hb.w); h[7] = bfh(hb.w);
        float t = y[0] * h[0] + y[1] * h[1] + y[2] * h[2] + y[3] * h[3] +
                  y[4] * h[4] + y[5] * h[5] + y[6] * h[6] + y[7] * h[7];
        t += __shfl_xor(t, 1);
        t += __shfl_xor(t, 2);
        t += __shfl_xor(t, 4);
        float p = exp2f(t * SC);
        d += p;
#pragma unroll
        for (int k = 0; k < 8; ++k) a[k] += p * h[k];
    }
    // merge the 4 groups (plain sums; 9 live values)
#pragma unroll
    for (int mask = 16; mask <= 32; mask <<= 1) {
        d += __shfl_xor(d, mask);
#pragma unroll
        for (int k = 0; k < 8; ++k) a[k] += __shfl_xor(a[k], mask);
    }
    if (qd == 0) {
        float inv = 1.f / fmaxf(d, 1e-16f);
        uint4 pk;
        pk.x = f2bf(a[0] * inv) | (f2bf(a[1] * inv) << 16);
        pk.y = f2bf(a[2] * inv) | (f2bf(a[3] * inv) << 16);
        pk.z = f2bf(a[4] * inv) | (f2bf(a[5] * inv) << 16);
        pk.w = f2bf(a[6] * inv) | (f2bf(a[7] * inv) << 16);
        *(uint4*)&a01[(size_t)i * 64 + hh * 32 + 4 * cb] = pk;
        if (cb == 0) sig2f[i * 2 + hh] = d > 0.f ? 1.f : 0.f;
    }
}

// ---------------- epi2: out = relu([a0|a1|h1]@B192 + sigma*bv + bs) + LDS pool ----
__global__ __launch_bounds__(256) void epi2(
        const ushort* __restrict__ a01, const ushort* __restrict__ h1b,
        const ushort* __restrict__ B192, const float* __restrict__ bv,
        const float* __restrict__ bs, const float* __restrict__ sig2,
        const int* __restrict__ batch, unsigned* __restrict__ pool, int n) {
    __shared__ float po[16][128];
    __shared__ int pg[16];
    int node0 = blockIdx.x * 16;
    int w = threadIdx.x >> 6, l = threadIdx.x & 63;
    int arow = node0 + (l & 15);
    int arc = (arow < n) ? arow : (n - 1);
    int koff = (l >> 4) << 3;
    s16x8 af[6];
    af[0] = *(const s16x8*)&a01[(size_t)arc * 128 + 0 + koff];
    af[1] = *(const s16x8*)&a01[(size_t)arc * 128 + 32 + koff];
    af[2] = *(const s16x8*)&a01[(size_t)arc * 128 + 64 + koff];
    af[3] = *(const s16x8*)&a01[(size_t)arc * 128 + 96 + koff];
    af[4] = *(const s16x8*)&h1b[(size_t)arc * 64 + 0 + koff];
    af[5] = *(const s16x8*)&h1b[(size_t)arc * 64 + 32 + koff];
    if (threadIdx.x < 16)
        pg[threadIdx.x] = (node0 + threadIdx.x < n) ? batch[node0 + threadIdx.x] : -1;
    int cl = l & 15;
#pragma unroll
    for (int qq = 0; qq < 2; ++qq) {
        int ct = w * 2 + qq;
        f32x4 acc = {0.f, 0.f, 0.f, 0.f};
#pragma unroll
        for (int ks = 0; ks < 6; ++ks) {
            s16x8 b = *(const s16x8*)&B192[(size_t)(ct * 6 + ks) * 512 + l * 8];
            acc = __builtin_amdgcn_mfma_f32_16x16x32_bf16(af[ks], b, acc, 0, 0, 0);
        }
        int cg = ct * 16 + cl;
        int head = cg >> 6;
        float bbs = bs[cg], bbv = bv[cg];
#pragma unroll
        for (int r = 0; r < 4; ++r) {
            int row = ((l >> 4) << 2) + r;
            int node = node0 + row;
            float sg = (node < n) ? sig2[node * 2 + head] : 0.f;
            po[row][cg] = fmaxf(acc[r] + sg * bbv + bbs, 0.f);
        }
    }
    __syncthreads();
    int t = threadIdx.x;
    if (t < 128) {
        int curg = -1;
        float mx = 0.f;
        for (int r = 0; r < 16; ++r) {
            int g = pg[r];
            if (g < 0) continue;
            if (g != curg) {
                if (curg >= 0) atomicMax(&pool[(size_t)curg * 128 + t], __float_as_uint(mx));
                curg = g;
                mx = 0.f;
            }
            mx = fmaxf(mx, po[r][t]);
        }
        if (curg >= 0) atomicMax(&pool[(size_t)curg * 128 + t], __float_as_uint(mx));
    }
}

// ---------------- MLP head ----------------
__global__ void head_kernel(const unsigned* __restrict__ pbits,
                            const float* __restrict__ W1, const float* __restrict__ b1,
                            const float* __restrict__ W2, const float* __restrict__ b2,
                            const float* __restrict__ W3, const float* __restrict__ b3,
                            float* __restrict__ out, int G) {
    int g = blockIdx.x;
    int t = threadIdx.x;  // 128 threads
    __shared__ float ps[128], xl[32], y[128];
    ps[t] = __uint_as_float(pbits[g * 128 + t]);
    __syncthreads();
    if (t < 32) {
        float a = b1[t];
        for (int k = 0; k < 128; ++k) a += ps[k] * W1[k * 32 + t];
        a = fmaxf(a, 0.f);
        xl[t] = a;
        out[G * 40 + g * 32 + t] = a;
    }
    __syncthreads();
    {
        float a = b2[t];
        for (int k = 0; k < 32; ++k) a += xl[k] * W2[k * 128 + t];
        y[t] = fmaxf(a, 0.f);
    }
    __syncthreads();
    if (t < 40) {
        float a = b3[t];
        for (int k = 0; k < 128; ++k) a += y[k] * W3[k * 40 + t];  // W3 is (128,40)
        out[g * 40 + t] = a;
    }
}

extern "C" void kernel_launch(void* const* d_in, const int* in_sizes, int n_in,
                              void* d_out, int out_size, void* d_ws, size_t ws_size,
                              hipStream_t stream) {
    const float* x = (const float*)d_in[0];
    const int* eidx = (const int*)d_in[1];
    const int* batch = (const int*)d_in[2];
    const float *Wq1 = (const float*)d_in[3], *bq1 = (const float*)d_in[4];
    const float *Wk1 = (const float*)d_in[5], *bk1 = (const float*)d_in[6];
    const float *Wv1 = (const float*)d_in[7], *bv1 = (const float*)d_in[8];
    const float *Ws1 = (const float*)d_in[9], *bs1 = (const float*)d_in[10];
    const float *Wq2 = (const float*)d_in[11], *bq2 = (const float*)d_in[12];
    const float *Wk2 = (const float*)d_in[13], *bk2 = (const float*)d_in[14];
    const float *Wv2 = (const float*)d_in[15], *bv2 = (const float*)d_in[16];
    const float *Ws2 = (const float*)d_in[17], *bs2 = (const float*)d_in[18];
    const float *W1 = (const float*)d_in[19], *b1 = (const float*)d_in[20];
    const float *W2 = (const float*)d_in[21], *b2 = (const float*)d_in[22];
    const float *W3 = (const float*)d_in[23], *b3 = (const float*)d_in[24];
    (void)bk1; (void)bk2;  // bk terms cancel in softmax (constant per-dst shift)

    const int N = in_sizes[0] / 3;
    const int E = in_sizes[1] / 2;
    const int G = out_size / 72;  // 40 + 32 per graph
    const int* esrc = eidx;
    const int* edst = eidx + E;
    const int NB = (N + 255) / 256;
    const int EB = (E + 255) / 256;
    const int POOLSZ = G * 128;
    const int PB = (POOLSZ + 255) / 256;
    const int RSIZE = (N + 7) / 8;  // dst-range size per XCD partition

    char* w = (char*)d_ws;
    size_t o = 0;
    auto alloc = [&](size_t bytes) {
        void* p = w + o;
        o = (o + bytes + 255) & ~(size_t)255;
        return p;
    };
    float* c1buf = (float*)alloc(24 * 4);
    float* wcat = (float*)alloc(128 * 4);
    ushort* bfragY = (ushort*)alloc(16 * 512 * 2);
    ushort* B192 = (ushort*)alloc(48 * 512 * 2);
    unsigned* h1b = (unsigned*)alloc((size_t)N * 32 * 4);   // N x 64 bf16
    ushort* Ypb = (ushort*)alloc((size_t)N * 128 * 2);      // N x 128 bf16
    unsigned* a01 = (unsigned*)alloc((size_t)N * 64 * 4);   // N x 128 bf16
    float* sig2 = (float*)alloc((size_t)N * 2 * 4);
    int* deg = (int*)alloc((size_t)N * 4);
    int* off = (int*)alloc((size_t)(N + 1) * 4);
    int* cursor = (int*)alloc((size_t)N * 4);
    int* srcs = (int*)alloc((size_t)E * 4);
    unsigned* pool = (unsigned*)alloc((size_t)POOLSZ * 4);
    int* bsum = (int*)alloc(256 * 4);
    (void)ws_size;

    // fused prep (weights -> c1/wcat/bfragY/B192) + zero deg + zero pool
    prep_all<<<45 + NB + PB, 256, 0, stream>>>(Wq1, bq1, Wk1, Wq2, bq2, Wk2, Wv2, Ws2,
                                               c1buf, wcat, bfragY, B192, deg, pool,
                                               N, NB, POOLSZ);

    // CSR by destination (XCD-partitioned atomics/writes)
    deg_part<<<8 * EB, 256, 0, stream>>>(edst, deg, E, RSIZE);
    scan_reduce<<<NB, 256, 0, stream>>>(deg, bsum, N);
    scan_apply<<<NB, 256, 0, stream>>>(deg, bsum, off, cursor, N, NB, E);
    scatter_part<<<8 * EB, 256, 0, stream>>>(esrc, edst, cursor, srcs, E, RSIZE);

    // layer 1 (fused, head-split lanes, paired edges)
    attn1f<<<(N + 15) / 16, 256, 0, stream>>>(x, c1buf, Wv1, bv1, Ws1, bs1, off, srcs,
                                              h1b, N);

    // layer 2
    lin2Y<<<(N + 15) / 16, 256, 0, stream>>>((const ushort*)h1b, bfragY, wcat, Ypb, N);
    attn2_kernel<<<(N + 3) / 4, 256, 0, stream>>>(Ypb, h1b, off, srcs, a01, sig2, N);
    epi2<<<(N + 15) / 16, 256, 0, stream>>>((const ushort*)a01, (const ushort*)h1b, B192,
                                            bv2, bs2, sig2, batch, pool, N);

    // head
    head_kernel<<<G, 128, 0, stream>>>(pool, W1, b1, W2, b2, W3, b3, (float*)d_out, G);
}